// Round 1
// baseline (385.041 us; speedup 1.0000x reference)
//
#include <hip/hip_runtime.h>
#include <math.h>

// RelativePositionAttention on MI355X (gfx950)
//
// Key algebraic simplifications (see reference):
//  - U_ortho @ U_ortho^T == I (square full-rank QR) -> skip projection entirely.
//  - theta depends only on (h, w, p) for VALID neighbors (drel == (dr,dc));
//    invalid ones are masked to -1e9 pre-softmax, so a (8,49,32) cos/sin
//    table computed from freqs is exact where it matters.
//  - neighbor validity recomputed analytically from n and w (bool input unused).
//
// Pipeline: build_table -> fused QKV SGEMM (fp32, 128x128x8 tile) ->
//           attention (1 wave per (b,h,n), lane = head-dim) -> W_O SGEMM.

#define BB 2
#define HGRID 48
#define WGRID 48
#define NNODE (HGRID*WGRID)   // 2304
#define RAD 3
#define WSZ 49
#define DMODEL 512
#define NHEAD 8
#define DHEAD 64
#define SCALE 0.125f
#define NEGV (-1e9f)

#define MROWS (BB*NNODE)      // 4608

// ---------------- cos/sin table: [NH][WSZ][32] ----------------
__global__ void build_table(const float* __restrict__ freqs,
                            float* __restrict__ costab, float* __restrict__ sintab) {
    int i = blockIdx.x * blockDim.x + threadIdx.x;    // NH*WSZ*32 = 12544
    if (i >= NHEAD * WSZ * 32) return;
    int p = i & 31;
    int w = (i >> 5) % WSZ;
    int h = i / (32 * WSZ);
    float dr = (float)(w / 7 - RAD);
    float dc = (float)(w % 7 - RAD);
    float th = dr * freqs[h * 64 + p] + dc * freqs[h * 64 + 32 + p];
    costab[i] = cosf(th);
    sintab[i] = sinf(th);
}

// ---------------- fp32 SGEMM, 128x128 tile, BK=8, 256 thr, 8x8/thread -------
// A: (4608 x 512) row-major. B matrices: (512 x 512) row-major.
// MODE 0: virtual N=1536 over [W_Q|W_K|W_V]; scatter C into Q/K/V laid out
//         as (B, H, N, D)  (index ((b*8+h)*2304+n)*64+d).
// MODE 1: N=512 plain row-major C.
template<int MODE>
__global__ __launch_bounds__(256)
void sgemm128(const float* __restrict__ A,
              const float* __restrict__ B0, const float* __restrict__ B1,
              const float* __restrict__ B2,
              float* __restrict__ C0, float* __restrict__ C1, float* __restrict__ C2) {
    __shared__ float As[8][128];
    __shared__ float Bs[8][128];

    const int tid = threadIdx.x;
    const int m0 = blockIdx.y * 128;
    const int n0 = blockIdx.x * 128;

    int t = 0, nb0 = n0;
    const float* Bp = B0;
    if (MODE == 0) {
        t = n0 >> 9;            // which of W_Q / W_K / W_V
        nb0 = n0 & 511;
        Bp = (t == 0) ? B0 : (t == 1) ? B1 : B2;
    }

    const int la_m = tid >> 1;          // 0..127
    const int la_k = (tid & 1) * 4;     // 0 or 4
    const int lb_k = tid >> 5;          // 0..7
    const int lb_n = (tid & 31) * 4;    // 0..124
    const int tx = tid & 15, ty = tid >> 4;

    float acc[8][8];
#pragma unroll
    for (int i = 0; i < 8; i++)
#pragma unroll
        for (int j = 0; j < 8; j++) acc[i][j] = 0.0f;

    for (int k0 = 0; k0 < DMODEL; k0 += 8) {
        float4 av = *(const float4*)&A[(size_t)(m0 + la_m) * DMODEL + k0 + la_k];
        As[la_k + 0][la_m] = av.x;
        As[la_k + 1][la_m] = av.y;
        As[la_k + 2][la_m] = av.z;
        As[la_k + 3][la_m] = av.w;
        *(float4*)&Bs[lb_k][lb_n] =
            *(const float4*)&Bp[(size_t)(k0 + lb_k) * 512 + nb0 + lb_n];
        __syncthreads();
#pragma unroll
        for (int kk = 0; kk < 8; kk++) {
            float a[8], b[8];
            *(float4*)&a[0] = *(const float4*)&As[kk][ty * 8];
            *(float4*)&a[4] = *(const float4*)&As[kk][ty * 8 + 4];
            *(float4*)&b[0] = *(const float4*)&Bs[kk][tx * 8];
            *(float4*)&b[4] = *(const float4*)&Bs[kk][tx * 8 + 4];
#pragma unroll
            for (int i = 0; i < 8; i++)
#pragma unroll
                for (int j = 0; j < 8; j++) acc[i][j] = fmaf(a[i], b[j], acc[i][j]);
        }
        __syncthreads();
    }

    if (MODE == 0) {
        float* Cp = (t == 0) ? C0 : (t == 1) ? C1 : C2;
        const int ccol = nb0 + tx * 8;       // within 512; 8-aligned
        const int h = ccol >> 6;
        const int d0 = ccol & 63;            // 8-aligned -> same head for all 8 j
#pragma unroll
        for (int i = 0; i < 8; i++) {
            const int r = m0 + ty * 8 + i;
            const int b_ = r / NNODE;
            const int n_ = r - b_ * NNODE;
            size_t base = ((size_t)((b_ * NHEAD + h) * NNODE + n_)) * 64 + d0;
            *(float4*)&Cp[base]     = *(const float4*)&acc[i][0];
            *(float4*)&Cp[base + 4] = *(const float4*)&acc[i][4];
        }
    } else {
#pragma unroll
        for (int i = 0; i < 8; i++) {
            const int r = m0 + ty * 8 + i;
            size_t base = (size_t)r * 512 + n0 + tx * 8;
            *(float4*)&C0[base]     = *(const float4*)&acc[i][0];
            *(float4*)&C0[base + 4] = *(const float4*)&acc[i][4];
        }
    }
}

// ---------------- attention: 1 wave per (b,h,n), lane = d ----------------
__global__ __launch_bounds__(256)
void attn_kernel(const float* __restrict__ Qf, const float* __restrict__ Kf,
                 const float* __restrict__ Vf, const int* __restrict__ nbr,
                 const float* __restrict__ costab, const float* __restrict__ sintab,
                 float* __restrict__ Af) {
    const int g = blockIdx.x * 4 + (threadIdx.x >> 6);   // (b*8+h)*2304 + n
    const int lane = threadIdx.x & 63;
    const int n = g % NNODE;
    const int bh = g / NNODE;          // 0..15
    const int h = bh & 7;

    const float* Kb = Kf + (size_t)bh * NNODE * 64;
    const float* Vb = Vf + (size_t)bh * NNODE * 64;
    const float q = Qf[(size_t)bh * NNODE * 64 + n * 64 + lane];

    const int idxv = (lane < WSZ) ? nbr[n * WSZ + lane] : 0;
    const int rr = n / WGRID, cc = n - (n / WGRID) * WGRID;

    const float* ct = costab + (size_t)h * WSZ * 32;
    const float* st = sintab + (size_t)h * WSZ * 32;
    const int p = lane >> 1;
    const float sign = (lane & 1) ? 1.0f : -1.0f;

    float myscore = -1e30f;
    for (int w = 0; w < WSZ; ++w) {
        const int row = __shfl(idxv, w);
        float kd = Kb[(size_t)row * 64 + lane];
        float kp = __shfl_xor(kd, 1);
        float c = ct[w * 32 + p], s = st[w * 32 + p];
        float kr = fmaf(sign * s, kp, c * kd);
        float v = q * kr;
        v += __shfl_xor(v, 1);  v += __shfl_xor(v, 2);  v += __shfl_xor(v, 4);
        v += __shfl_xor(v, 8);  v += __shfl_xor(v, 16); v += __shfl_xor(v, 32);
        float sc = v * SCALE;
        const int dr = w / 7 - RAD, dc = w % 7 - RAD;
        const int nr = rr + dr, nc = cc + dc;
        if (!(nr >= 0 && nr < HGRID && nc >= 0 && nc < WGRID)) sc = NEGV;
        if (lane == w) myscore = sc;
    }

    float m = myscore;
    for (int o = 1; o < 64; o <<= 1) m = fmaxf(m, __shfl_xor(m, o));
    float e = (lane < WSZ) ? expf(myscore - m) : 0.0f;
    float ssum = e;
    for (int o = 1; o < 64; o <<= 1) ssum += __shfl_xor(ssum, o);
    const float wsm = e / ssum;

    float acc = 0.0f;
    for (int w = 0; w < WSZ; ++w) {
        const float wv = __shfl(wsm, w);
        const int row = __shfl(idxv, w);
        acc = fmaf(wv, Vb[(size_t)row * 64 + lane], acc);
    }

    const int b_ = bh >> 3;
    Af[((size_t)(b_ * NNODE + n)) * 512 + h * 64 + lane] = acc;
}

extern "C" void kernel_launch(void* const* d_in, const int* in_sizes, int n_in,
                              void* d_out, int out_size, void* d_ws, size_t ws_size,
                              hipStream_t stream) {
    const float* x     = (const float*)d_in[0];
    const float* WQ    = (const float*)d_in[2];
    const float* WK    = (const float*)d_in[3];
    const float* WV    = (const float*)d_in[4];
    const float* WO    = (const float*)d_in[5];
    const float* freqs = (const float*)d_in[7];
    const int*   nbr   = (const int*)d_in[8];

    const size_t TEN = (size_t)MROWS * DMODEL;   // 2,359,296 floats
    float* ws   = (float*)d_ws;
    float* Qf   = ws;
    float* Kf   = Qf + TEN;
    float* Vf   = Kf + TEN;
    float* Af   = Vf + TEN;
    float* ctab = Af + TEN;
    float* stab = ctab + NHEAD * WSZ * 32;

    build_table<<<49, 256, 0, stream>>>(freqs, ctab, stab);

    dim3 gqkv(12, 36);   // 1536/128 cols x 4608/128 rows
    sgemm128<0><<<gqkv, 256, 0, stream>>>(x, WQ, WK, WV, Qf, Kf, Vf);

    attn_kernel<<<(BB * NHEAD * NNODE) / 4, 256, 0, stream>>>(Qf, Kf, Vf, nbr, ctab, stab, Af);

    dim3 go(4, 36);      // 512/128 x 4608/128
    sgemm128<1><<<go, 256, 0, stream>>>(Af, WO, nullptr, nullptr,
                                        (float*)d_out, nullptr, nullptr);
}

// Round 2
// 294.878 us; speedup vs baseline: 1.3058x; 1.3058x over previous
//
#include <hip/hip_runtime.h>
#include <math.h>

// RelativePositionAttention on MI355X (gfx950)
//
// Algebraic simplifications (verified round 1, absmax 3.9e-3):
//  - U_ortho @ U_ortho^T == I (square full-rank QR) -> skip projection.
//  - theta depends only on (h, w, p) for VALID neighbors; invalid ones are
//    masked pre-softmax, so an (8,49,32) cos/sin table is exact where needed.
//  - neighbor validity recomputed analytically from n and w.
//
// Round 2: attention rewritten lane-parallel-over-neighbors (w = lane) to
// kill the 49x serial shuffle-reduce chains (previous: 221 us, VALUBusy 43%).

#define BB 2
#define HGRID 48
#define WGRID 48
#define NNODE (HGRID*WGRID)   // 2304
#define RAD 3
#define WSZ 49
#define DMODEL 512
#define NHEAD 8
#define DHEAD 64
#define SCALE 0.125f
#define NEGV (-1e9f)

#define MROWS (BB*NNODE)      // 4608
#define WPAD 33               // float2 stride for LDS cos/sin table

// ---------------- combined cos/sin table: tab[h][w][p] = (cos, sin) --------
__global__ void build_table2(const float* __restrict__ freqs,
                             float2* __restrict__ tab) {
    int i = blockIdx.x * blockDim.x + threadIdx.x;    // NH*WSZ*32 = 12544
    if (i >= NHEAD * WSZ * 32) return;
    int p = i & 31;
    int w = (i >> 5) % WSZ;
    int h = i / (32 * WSZ);
    float dr = (float)(w / 7 - RAD);
    float dc = (float)(w % 7 - RAD);
    float th = dr * freqs[h * 64 + p] + dc * freqs[h * 64 + 32 + p];
    tab[i] = make_float2(cosf(th), sinf(th));
}

// ---------------- fp32 SGEMM, 128x128 tile, BK=8, 256 thr, 8x8/thread -------
template<int MODE>
__global__ __launch_bounds__(256)
void sgemm128(const float* __restrict__ A,
              const float* __restrict__ B0, const float* __restrict__ B1,
              const float* __restrict__ B2,
              float* __restrict__ C0, float* __restrict__ C1, float* __restrict__ C2) {
    __shared__ float As[8][128];
    __shared__ float Bs[8][128];

    const int tid = threadIdx.x;
    const int m0 = blockIdx.y * 128;
    const int n0 = blockIdx.x * 128;

    int t = 0, nb0 = n0;
    const float* Bp = B0;
    if (MODE == 0) {
        t = n0 >> 9;
        nb0 = n0 & 511;
        Bp = (t == 0) ? B0 : (t == 1) ? B1 : B2;
    }

    const int la_m = tid >> 1;
    const int la_k = (tid & 1) * 4;
    const int lb_k = tid >> 5;
    const int lb_n = (tid & 31) * 4;
    const int tx = tid & 15, ty = tid >> 4;

    float acc[8][8];
#pragma unroll
    for (int i = 0; i < 8; i++)
#pragma unroll
        for (int j = 0; j < 8; j++) acc[i][j] = 0.0f;

    for (int k0 = 0; k0 < DMODEL; k0 += 8) {
        float4 av = *(const float4*)&A[(size_t)(m0 + la_m) * DMODEL + k0 + la_k];
        As[la_k + 0][la_m] = av.x;
        As[la_k + 1][la_m] = av.y;
        As[la_k + 2][la_m] = av.z;
        As[la_k + 3][la_m] = av.w;
        *(float4*)&Bs[lb_k][lb_n] =
            *(const float4*)&Bp[(size_t)(k0 + lb_k) * 512 + nb0 + lb_n];
        __syncthreads();
#pragma unroll
        for (int kk = 0; kk < 8; kk++) {
            float a[8], b[8];
            *(float4*)&a[0] = *(const float4*)&As[kk][ty * 8];
            *(float4*)&a[4] = *(const float4*)&As[kk][ty * 8 + 4];
            *(float4*)&b[0] = *(const float4*)&Bs[kk][tx * 8];
            *(float4*)&b[4] = *(const float4*)&Bs[kk][tx * 8 + 4];
#pragma unroll
            for (int i = 0; i < 8; i++)
#pragma unroll
                for (int j = 0; j < 8; j++) acc[i][j] = fmaf(a[i], b[j], acc[i][j]);
        }
        __syncthreads();
    }

    if (MODE == 0) {
        float* Cp = (t == 0) ? C0 : (t == 1) ? C1 : C2;
        const int ccol = nb0 + tx * 8;
        const int h = ccol >> 6;
        const int d0 = ccol & 63;
#pragma unroll
        for (int i = 0; i < 8; i++) {
            const int r = m0 + ty * 8 + i;
            const int b_ = r / NNODE;
            const int n_ = r - b_ * NNODE;
            size_t base = ((size_t)((b_ * NHEAD + h) * NNODE + n_)) * 64 + d0;
            *(float4*)&Cp[base]     = *(const float4*)&acc[i][0];
            *(float4*)&Cp[base + 4] = *(const float4*)&acc[i][4];
        }
    } else {
#pragma unroll
        for (int i = 0; i < 8; i++) {
            const int r = m0 + ty * 8 + i;
            size_t base = (size_t)r * 512 + n0 + tx * 8;
            *(float4*)&C0[base]     = *(const float4*)&acc[i][0];
            *(float4*)&C0[base + 4] = *(const float4*)&acc[i][4];
        }
    }
}

// ---------------- attention v2: lane = neighbor w (scores), 4 waves/block ---
// All 4 waves of a block share bh (2304 % 4 == 0, blocks start at g % 4 == 0).
__global__ __launch_bounds__(256)
void attn2(const float* __restrict__ Qf, const float* __restrict__ Kf,
           const float* __restrict__ Vf, const int* __restrict__ nbr,
           const float2* __restrict__ tab, float* __restrict__ Af) {
    __shared__ float2 cs[WSZ * WPAD];   // padded (cos,sin) for this head
    __shared__ float  qs[4][64];
    __shared__ float2 pv[4][52];        // (softmax weight, row-as-float)

    const int tid  = threadIdx.x;
    const int wid  = tid >> 6;
    const int lane = tid & 63;
    const int g0   = blockIdx.x * 4;
    const int bh   = g0 / NNODE;        // same for all 4 waves
    const int h    = bh & 7;

    // stage (cos,sin) table slice for this head, stride-33 padded
    for (int i = tid; i < WSZ * 32; i += 256) {
        int w_ = i >> 5, p_ = i & 31;
        cs[w_ * WPAD + p_] = tab[(h * WSZ + w_) * 32 + p_];
    }

    const int g = g0 + wid;
    const int n = g - bh * NNODE;
    const float* Kb = Kf + (size_t)bh * NNODE * 64;
    const float* Vb = Vf + (size_t)bh * NNODE * 64;

    qs[wid][lane] = Qf[(size_t)bh * NNODE * 64 + (size_t)n * 64 + lane];
    __syncthreads();

    // ---- score phase: lane w computes its full rotated dot product ----
    const int w = lane;
    float score = -1e30f;
    int row = 0;
    if (w < WSZ) {
        row = nbr[n * WSZ + w];
        const int rr = n / WGRID, ccol = n - (n / WGRID) * WGRID;
        const int nr = rr + (w / 7 - RAD), nc = ccol + (w % 7 - RAD);
        const bool valid = (nr >= 0 && nr < HGRID && nc >= 0 && nc < WGRID);

        const float* krow = Kb + (size_t)row * 64;
        float s = 0.0f;
#pragma unroll
        for (int s4 = 0; s4 < 16; ++s4) {
            float4 k4 = *(const float4*)&krow[s4 * 4];
            float4 q4 = *(const float4*)&qs[wid][s4 * 4];      // LDS broadcast
            float2 c0 = cs[w * WPAD + 2 * s4];
            float2 c1 = cs[w * WPAD + 2 * s4 + 1];
            s += q4.x * (c0.x * k4.x - c0.y * k4.y)
               + q4.y * (c0.y * k4.x + c0.x * k4.y)
               + q4.z * (c1.x * k4.z - c1.y * k4.w)
               + q4.w * (c1.y * k4.z + c1.x * k4.w);
        }
        score = valid ? s * SCALE : NEGV;
    }

    // ---- softmax across lanes (single reduction) ----
    float m = score;
#pragma unroll
    for (int o = 1; o < 64; o <<= 1) m = fmaxf(m, __shfl_xor(m, o));
    float e = (w < WSZ) ? __expf(score - m) : 0.0f;
    float ssum = e;
#pragma unroll
    for (int o = 1; o < 64; o <<= 1) ssum += __shfl_xor(ssum, o);
    const float wsm = e / ssum;

    if (w < WSZ) pv[wid][w] = make_float2(wsm, __int_as_float(row));
    asm volatile("s_waitcnt lgkmcnt(0)" ::: "memory");   // wave-local LDS dep

    // ---- PV phase: 4 lane-groups x 16 lanes, float4 over d ----
    const int grp = lane >> 4;
    const int dq  = lane & 15;
    float4 acc = make_float4(0.f, 0.f, 0.f, 0.f);
    for (int w2 = grp; w2 < WSZ; w2 += 4) {
        float2 pr = pv[wid][w2];                         // LDS broadcast
        const float* vrow = Vb + (size_t)__float_as_int(pr.y) * 64;
        float4 v4 = *(const float4*)&vrow[dq * 4];
        acc.x = fmaf(pr.x, v4.x, acc.x);
        acc.y = fmaf(pr.x, v4.y, acc.y);
        acc.z = fmaf(pr.x, v4.z, acc.z);
        acc.w = fmaf(pr.x, v4.w, acc.w);
    }
    acc.x += __shfl_xor(acc.x, 16); acc.y += __shfl_xor(acc.y, 16);
    acc.z += __shfl_xor(acc.z, 16); acc.w += __shfl_xor(acc.w, 16);
    acc.x += __shfl_xor(acc.x, 32); acc.y += __shfl_xor(acc.y, 32);
    acc.z += __shfl_xor(acc.z, 32); acc.w += __shfl_xor(acc.w, 32);

    if (grp == 0) {
        const int b_ = bh >> 3;
        *(float4*)&Af[((size_t)(b_ * NNODE + n)) * 512 + h * 64 + dq * 4] = acc;
    }
}

extern "C" void kernel_launch(void* const* d_in, const int* in_sizes, int n_in,
                              void* d_out, int out_size, void* d_ws, size_t ws_size,
                              hipStream_t stream) {
    const float* x     = (const float*)d_in[0];
    const float* WQ    = (const float*)d_in[2];
    const float* WK    = (const float*)d_in[3];
    const float* WV    = (const float*)d_in[4];
    const float* WO    = (const float*)d_in[5];
    const float* freqs = (const float*)d_in[7];
    const int*   nbr   = (const int*)d_in[8];

    const size_t TEN = (size_t)MROWS * DMODEL;   // 2,359,296 floats
    float*  ws  = (float*)d_ws;
    float*  Qf  = ws;
    float*  Kf  = Qf + TEN;
    float*  Vf  = Kf + TEN;
    float*  Af  = Vf + TEN;
    float2* tab = (float2*)(Af + TEN);           // NH*WSZ*32 float2

    build_table2<<<49, 256, 0, stream>>>(freqs, tab);

    dim3 gqkv(12, 36);
    sgemm128<0><<<gqkv, 256, 0, stream>>>(x, WQ, WK, WV, Qf, Kf, Vf);

    attn2<<<(BB * NHEAD * NNODE) / 4, 256, 0, stream>>>(Qf, Kf, Vf, nbr, tab, Af);

    dim3 go(4, 36);
    sgemm128<1><<<go, 256, 0, stream>>>(Af, WO, nullptr, nullptr,
                                        (float*)d_out, nullptr, nullptr);
}

// Round 3
// 198.323 us; speedup vs baseline: 1.9415x; 1.4869x over previous
//
#include <hip/hip_runtime.h>
#include <math.h>

// RelativePositionAttention on MI355X (gfx950)
//
// Algebraic simplifications (verified rounds 1-2, absmax 3.9e-3):
//  - U_ortho @ U_ortho^T == I -> skip QR projection entirely.
//  - RoPE angles collapse to an (8,49,32) table; invalid neighbors masked.
//  - neighbor validity recomputed analytically from n and w.
//
// Round 3: GEMMs moved to bf16 MFMA (16x16x32) with hi/lo split-K:
//   A*B ~= A_hi*B_hi + A_lo*B_hi + A_hi*B_lo  as ONE GEMM with K=1536
//   (A fold-at-1024 over physical [hi|lo] 1024-wide buffer; B'^T built
//   pre-transposed with [hi|hi|lo] blocks). m97 structure: 128^2 tile,
//   BK=64, global_load_lds(16B) + pre-swizzled source + XOR ds_read.

#define BB 2
#define HGRID 48
#define WGRID 48
#define NNODE (HGRID*WGRID)   // 2304
#define RAD 3
#define WSZ 49
#define DMODEL 512
#define NHEAD 8
#define SCALE 0.125f
#define NEGV (-1e9f)
#define MROWS (BB*NNODE)      // 4608
#define WPAD 33
#define TEN ((size_t)MROWS*DMODEL)

typedef unsigned short u16;
typedef __attribute__((ext_vector_type(8))) short bf16x8;
typedef __attribute__((ext_vector_type(4))) float f32x4;

__device__ __forceinline__ u16 f2bf(float f) {
    unsigned u = __float_as_uint(f);
    return (u16)((u + 0x7FFFu + ((u >> 16) & 1u)) >> 16);
}
__device__ __forceinline__ float bf2f(u16 s) {
    return __uint_as_float(((unsigned)s) << 16);
}

// ---------------- combined cos/sin table ----------------
__global__ void build_table2(const float* __restrict__ freqs,
                             float2* __restrict__ tab) {
    int i = blockIdx.x * blockDim.x + threadIdx.x;
    if (i >= NHEAD * WSZ * 32) return;
    int p = i & 31;
    int w = (i >> 5) % WSZ;
    int h = i / (32 * WSZ);
    float dr = (float)(w / 7 - RAD);
    float dc = (float)(w % 7 - RAD);
    float th = dr * freqs[h * 64 + p] + dc * freqs[h * 64 + 32 + p];
    tab[i] = make_float2(cosf(th), sinf(th));
}

// ---------------- x -> [hi | lo] bf16, row width 1024 ----------------
__global__ void conv_x(const float* __restrict__ x, u16* __restrict__ x2) {
    int id = blockIdx.x * 256 + threadIdx.x;         // MROWS*128
    if (id >= MROWS * 128) return;
    int r = id >> 7, c4 = (id & 127) << 2;
    float4 v = *(const float4*)&x[(size_t)r * 512 + c4];
    ushort4 hi, lo;
    hi.x = f2bf(v.x); lo.x = f2bf(v.x - bf2f(hi.x));
    hi.y = f2bf(v.y); lo.y = f2bf(v.y - bf2f(hi.y));
    hi.z = f2bf(v.z); lo.z = f2bf(v.z - bf2f(hi.z));
    hi.w = f2bf(v.w); lo.w = f2bf(v.w - bf2f(hi.w));
    *(ushort4*)&x2[(size_t)r * 1024 + c4]       = hi;
    *(ushort4*)&x2[(size_t)r * 1024 + 512 + c4] = lo;
}

// ------- W (512 x 512 row-major, [k][n]) -> B'^T [n'][k'=0..1535] --------
// k'<512: hi(W[k'][n]); k'<1024: hi(W[k'-512][n]); else lo(W[k'-1024][n]).
template<int NW>
__global__ void conv_w(const float* __restrict__ S0, const float* __restrict__ S1,
                       const float* __restrict__ S2, u16* __restrict__ dst) {
    int id = blockIdx.x * 256 + threadIdx.x;         // NW*192
    if (id >= NW * 192) return;
    int np = id % NW;
    int kb = (id / NW) * 8;
    const float* S = S0;
    int n = np;
    if (NW == 1536) { int t = np >> 9; n = np & 511; S = (t==0)?S0:(t==1)?S1:S2; }
    u16 out[8];
#pragma unroll
    for (int i = 0; i < 8; ++i) {
        int kp = kb + i;
        int kf = kp & 511;
        float wv = S[(size_t)kf * 512 + n];
        u16 h = f2bf(wv);
        out[i] = (kp < 1024) ? h : f2bf(wv - bf2f(h));
    }
    *(ushort4*)&dst[(size_t)np * 1536 + kb]     = *(ushort4*)&out[0];
    *(ushort4*)&dst[(size_t)np * 1536 + kb + 4] = *(ushort4*)&out[4];
}

// ---------------- bf16 MFMA GEMM: 128x128 tile, BK=64, 4 waves ----------
// A: M x 1024 bf16 (fold k'>=1024 -> k'-1024). Bt: NB x 1536 bf16.
// MODE 0: NB=1536, scatter C -> Qf/Kf/Vf (bh,n,d). MODE 1: NB=512, C row-major.
template<int MODE>
__global__ __launch_bounds__(256)
void mgemm(const u16* __restrict__ A, const u16* __restrict__ Bt,
           float* __restrict__ C0, float* __restrict__ C1, float* __restrict__ C2) {
    __shared__ u16 As[128 * 64];
    __shared__ u16 Bs[128 * 64];

    const int tid = threadIdx.x;
    const int l = tid & 63, wid = tid >> 6;
    const int m0 = blockIdx.y * 128;
    const int n0 = blockIdx.x * 128;
    const int wm = (wid >> 1) * 64, wn = (wid & 1) * 64;
    const int fr = l & 15, fk = l >> 4;
    const int srow = l >> 3, slot = l & 7;

    f32x4 acc[4][4];
#pragma unroll
    for (int m = 0; m < 4; ++m)
#pragma unroll
        for (int n = 0; n < 4; ++n) acc[m][n] = (f32x4){0.f, 0.f, 0.f, 0.f};

    for (int kt = 0; kt < 24; ++kt) {
        const int k0 = kt * 64;
        const int k0A = (k0 >= 1024) ? (k0 - 1024) : k0;
#pragma unroll
        for (int j = 0; j < 4; ++j) {
            const int r = wid * 32 + j * 8 + srow;
            const int cA = (slot ^ (r & 7)) * 8;       // pre-swizzled source
            const u16* gA = A + (size_t)(m0 + r) * 1024 + k0A + cA;
            __builtin_amdgcn_global_load_lds(
                (const __attribute__((address_space(1))) unsigned int*)gA,
                (__attribute__((address_space(3))) unsigned int*)(As + wid * 2048 + j * 512),
                16, 0, 0);
            const u16* gB = Bt + (size_t)(n0 + r) * 1536 + k0 + cA;
            __builtin_amdgcn_global_load_lds(
                (const __attribute__((address_space(1))) unsigned int*)gB,
                (__attribute__((address_space(3))) unsigned int*)(Bs + wid * 2048 + j * 512),
                16, 0, 0);
        }
        asm volatile("s_waitcnt vmcnt(0)" ::: "memory");
        __syncthreads();

        bf16x8 af[4][2], bf[4][2];
#pragma unroll
        for (int m = 0; m < 4; ++m) {
            const int row = wm + m * 16 + fr;
#pragma unroll
            for (int kk = 0; kk < 2; ++kk) {
                const int b = (kk * 64 + fk * 16) ^ ((row & 7) << 4);   // swz read
                af[m][kk] = *(const bf16x8*)((const char*)As + row * 128 + b);
            }
        }
#pragma unroll
        for (int n = 0; n < 4; ++n) {
            const int row = wn + n * 16 + fr;
#pragma unroll
            for (int kk = 0; kk < 2; ++kk) {
                const int b = (kk * 64 + fk * 16) ^ ((row & 7) << 4);
                bf[n][kk] = *(const bf16x8*)((const char*)Bs + row * 128 + b);
            }
        }
#pragma unroll
        for (int kk = 0; kk < 2; ++kk)
#pragma unroll
            for (int m = 0; m < 4; ++m)
#pragma unroll
                for (int n = 0; n < 4; ++n)
                    acc[m][n] = __builtin_amdgcn_mfma_f32_16x16x32_bf16(
                        af[m][kk], bf[n][kk], acc[m][n], 0, 0, 0);
        __syncthreads();
    }

    // epilogue: C/D layout col = lane&15, row = (lane>>4)*4 + i  [m89]
    if (MODE == 0) {
#pragma unroll
        for (int nf = 0; nf < 4; ++nf) {
            const int ccol = n0 + wn + nf * 16 + fr;
            const int t = ccol >> 9;
            const int h = (ccol >> 6) & 7;
            const int d = ccol & 63;
            float* Cp = (t == 0) ? C0 : (t == 1) ? C1 : C2;
#pragma unroll
            for (int mf = 0; mf < 4; ++mf) {
#pragma unroll
                for (int i = 0; i < 4; ++i) {
                    const int grow = m0 + wm + mf * 16 + fk * 4 + i;
                    const int b_ = grow / NNODE;
                    const int nn = grow - b_ * NNODE;
                    Cp[((size_t)((b_ * NHEAD + h) * NNODE + nn)) * 64 + d] = acc[mf][nf][i];
                }
            }
        }
    } else {
#pragma unroll
        for (int nf = 0; nf < 4; ++nf) {
            const int ccol = n0 + wn + nf * 16 + fr;
#pragma unroll
            for (int mf = 0; mf < 4; ++mf) {
#pragma unroll
                for (int i = 0; i < 4; ++i) {
                    const int grow = m0 + wm + mf * 16 + fk * 4 + i;
                    C0[(size_t)grow * 512 + ccol] = acc[mf][nf][i];
                }
            }
        }
    }
}

// ---------------- attention: lane = neighbor w, 4 waves/block ----------
__global__ __launch_bounds__(256)
void attn2(const float* __restrict__ Qf, const float* __restrict__ Kf,
           const float* __restrict__ Vf, const int* __restrict__ nbr,
           const float2* __restrict__ tab, u16* __restrict__ out2) {
    __shared__ float2 cs[WSZ * WPAD];
    __shared__ float  qs[4][64];
    __shared__ float2 pv[4][52];

    const int tid  = threadIdx.x;
    const int wid  = tid >> 6;
    const int lane = tid & 63;
    const int g0   = blockIdx.x * 4;
    const int bh   = g0 / NNODE;
    const int h    = bh & 7;

    for (int i = tid; i < WSZ * 32; i += 256) {
        int w_ = i >> 5, p_ = i & 31;
        cs[w_ * WPAD + p_] = tab[(h * WSZ + w_) * 32 + p_];
    }

    const int g = g0 + wid;
    const int n = g - bh * NNODE;
    const float* Kb = Kf + (size_t)bh * NNODE * 64;
    const float* Vb = Vf + (size_t)bh * NNODE * 64;

    qs[wid][lane] = Qf[(size_t)bh * NNODE * 64 + (size_t)n * 64 + lane];
    __syncthreads();

    const int w = lane;
    float score = -1e30f;
    int row = 0;
    if (w < WSZ) {
        row = nbr[n * WSZ + w];
        const int rr = n / WGRID, ccol = n - (n / WGRID) * WGRID;
        const int nr = rr + (w / 7 - RAD), nc = ccol + (w % 7 - RAD);
        const bool valid = (nr >= 0 && nr < HGRID && nc >= 0 && nc < WGRID);

        const float* krow = Kb + (size_t)row * 64;
        float s = 0.0f;
#pragma unroll
        for (int s4 = 0; s4 < 16; ++s4) {
            float4 k4 = *(const float4*)&krow[s4 * 4];
            float4 q4 = *(const float4*)&qs[wid][s4 * 4];
            float2 c0 = cs[w * WPAD + 2 * s4];
            float2 c1 = cs[w * WPAD + 2 * s4 + 1];
            s += q4.x * (c0.x * k4.x - c0.y * k4.y)
               + q4.y * (c0.y * k4.x + c0.x * k4.y)
               + q4.z * (c1.x * k4.z - c1.y * k4.w)
               + q4.w * (c1.y * k4.z + c1.x * k4.w);
        }
        score = valid ? s * SCALE : NEGV;
    }

    float m = score;
#pragma unroll
    for (int o = 1; o < 64; o <<= 1) m = fmaxf(m, __shfl_xor(m, o));
    float e = (w < WSZ) ? __expf(score - m) : 0.0f;
    float ssum = e;
#pragma unroll
    for (int o = 1; o < 64; o <<= 1) ssum += __shfl_xor(ssum, o);
    const float wsm = e / ssum;

    if (w < WSZ) pv[wid][w] = make_float2(wsm, __int_as_float(row));
    asm volatile("s_waitcnt lgkmcnt(0)" ::: "memory");

    const int grp = lane >> 4;
    const int dq  = lane & 15;
    float4 acc = make_float4(0.f, 0.f, 0.f, 0.f);
    for (int w2 = grp; w2 < WSZ; w2 += 4) {
        float2 pr = pv[wid][w2];
        const float* vrow = Vb + (size_t)__float_as_int(pr.y) * 64;
        float4 v4 = *(const float4*)&vrow[dq * 4];
        acc.x = fmaf(pr.x, v4.x, acc.x);
        acc.y = fmaf(pr.x, v4.y, acc.y);
        acc.z = fmaf(pr.x, v4.z, acc.z);
        acc.w = fmaf(pr.x, v4.w, acc.w);
    }
    acc.x += __shfl_xor(acc.x, 16); acc.y += __shfl_xor(acc.y, 16);
    acc.z += __shfl_xor(acc.z, 16); acc.w += __shfl_xor(acc.w, 16);
    acc.x += __shfl_xor(acc.x, 32); acc.y += __shfl_xor(acc.y, 32);
    acc.z += __shfl_xor(acc.z, 32); acc.w += __shfl_xor(acc.w, 32);

    if (grp == 0) {
        const int b_ = bh >> 3;
        const size_t rowb = (size_t)(b_ * NNODE + n) * 1024 + h * 64 + dq * 4;
        ushort4 hi, lo;
        hi.x = f2bf(acc.x); lo.x = f2bf(acc.x - bf2f(hi.x));
        hi.y = f2bf(acc.y); lo.y = f2bf(acc.y - bf2f(hi.y));
        hi.z = f2bf(acc.z); lo.z = f2bf(acc.z - bf2f(hi.z));
        hi.w = f2bf(acc.w); lo.w = f2bf(acc.w - bf2f(hi.w));
        *(ushort4*)&out2[rowb]       = hi;
        *(ushort4*)&out2[rowb + 512] = lo;
    }
}

extern "C" void kernel_launch(void* const* d_in, const int* in_sizes, int n_in,
                              void* d_out, int out_size, void* d_ws, size_t ws_size,
                              hipStream_t stream) {
    const float* x     = (const float*)d_in[0];
    const float* WQ    = (const float*)d_in[2];
    const float* WK    = (const float*)d_in[3];
    const float* WV    = (const float*)d_in[4];
    const float* WO    = (const float*)d_in[5];
    const float* freqs = (const float*)d_in[7];
    const int*   nbr   = (const int*)d_in[8];

    float*  Qf  = (float*)d_ws;
    float*  Kf  = Qf + TEN;
    float*  Vf  = Kf + TEN;
    float2* tab = (float2*)(Vf + TEN);                 // 12544 float2
    u16*    x2  = (u16*)(tab + 12544);                 // MROWS x 1024
    u16*    Wq2 = x2 + (size_t)MROWS * 1024;           // 1536 x 1536
    u16*    Wo2 = Wq2 + (size_t)1536 * 1536;           // 512 x 1536

    build_table2<<<49, 256, 0, stream>>>(freqs, tab);
    conv_x<<<(MROWS * 128 + 255) / 256, 256, 0, stream>>>(x, x2);
    conv_w<1536><<<(1536 * 192 + 255) / 256, 256, 0, stream>>>(WQ, WK, WV, Wq2);
    conv_w<512><<<(512 * 192 + 255) / 256, 256, 0, stream>>>(WO, WO, WO, Wo2);

    dim3 gqkv(12, 36);
    mgemm<0><<<gqkv, 256, 0, stream>>>(x2, Wq2, Qf, Kf, Vf);

    attn2<<<(BB * NHEAD * NNODE) / 4, 256, 0, stream>>>(Qf, Kf, Vf, nbr, tab, x2);

    dim3 go(4, 36);
    mgemm<1><<<go, 256, 0, stream>>>(x2, Wo2, (float*)d_out, nullptr, nullptr);
}

// Round 4
// 147.861 us; speedup vs baseline: 2.6041x; 1.3413x over previous
//
#include <hip/hip_runtime.h>
#include <math.h>

// RelativePositionAttention on MI355X (gfx950)
//
// Algebraic simplifications (verified rounds 1-3, absmax 3.9e-3):
//  - U_ortho @ U_ortho^T == I -> skip QR projection entirely.
//  - RoPE relative rotation factorizes: score = Re(conj(q e^{i th_q}) k e^{i th_k})
//    with th = r*f_r + c*f_c  -> pre-rotate Q,K by absolute position ONCE;
//    attention becomes plain masked sliding-window attention (no table, no
//    neighbor_index needed - indices/validity recomputed analytically).
//  - GEMMs: bf16 MFMA hi/lo split-K (K=1536) as one GEMM, m97 structure.
//
// Round 4: attention = spatially-tiled LDS-staged kernel (4x8 query tile,
// <=140-row K/V halo staged coalesced, fp32 VALU dots from LDS) replacing
// the scatter-load kernel (111 us, latency-bound, VALUBusy 29%).

#define BB 2
#define HGRID 48
#define WGRID 48
#define NNODE (HGRID*WGRID)   // 2304
#define RAD 3
#define WSZ 49
#define DMODEL 512
#define NHEAD 8
#define SCALE 0.125f
#define MROWS (BB*NNODE)      // 4608
#define TEN ((size_t)MROWS*DMODEL)

typedef unsigned short u16;
typedef __attribute__((ext_vector_type(8))) short bf16x8;
typedef __attribute__((ext_vector_type(4))) float f32x4;

__device__ __forceinline__ u16 f2bf(float f) {
    unsigned u = __float_as_uint(f);
    return (u16)((u + 0x7FFFu + ((u >> 16) & 1u)) >> 16);
}
__device__ __forceinline__ float bf2f(u16 s) {
    return __uint_as_float(((unsigned)s) << 16);
}

// ---------------- x -> [hi | lo] bf16, row width 1024 ----------------
__global__ void conv_x(const float* __restrict__ x, u16* __restrict__ x2) {
    int id = blockIdx.x * 256 + threadIdx.x;         // MROWS*128
    if (id >= MROWS * 128) return;
    int r = id >> 7, c4 = (id & 127) << 2;
    float4 v = *(const float4*)&x[(size_t)r * 512 + c4];
    ushort4 hi, lo;
    hi.x = f2bf(v.x); lo.x = f2bf(v.x - bf2f(hi.x));
    hi.y = f2bf(v.y); lo.y = f2bf(v.y - bf2f(hi.y));
    hi.z = f2bf(v.z); lo.z = f2bf(v.z - bf2f(hi.z));
    hi.w = f2bf(v.w); lo.w = f2bf(v.w - bf2f(hi.w));
    *(ushort4*)&x2[(size_t)r * 1024 + c4]       = hi;
    *(ushort4*)&x2[(size_t)r * 1024 + 512 + c4] = lo;
}

// ------- W (512 x 512 row-major) -> B'^T [n'][k'=0..1535] --------
template<int NW>
__global__ void conv_w(const float* __restrict__ S0, const float* __restrict__ S1,
                       const float* __restrict__ S2, u16* __restrict__ dst) {
    int id = blockIdx.x * 256 + threadIdx.x;         // NW*192
    if (id >= NW * 192) return;
    int np = id % NW;
    int kb = (id / NW) * 8;
    const float* S = S0;
    int n = np;
    if (NW == 1536) { int t = np >> 9; n = np & 511; S = (t==0)?S0:(t==1)?S1:S2; }
    u16 out[8];
#pragma unroll
    for (int i = 0; i < 8; ++i) {
        int kp = kb + i;
        int kf = kp & 511;
        float wv = S[(size_t)kf * 512 + n];
        u16 h = f2bf(wv);
        out[i] = (kp < 1024) ? h : f2bf(wv - bf2f(h));
    }
    *(ushort4*)&dst[(size_t)np * 1536 + kb]     = *(ushort4*)&out[0];
    *(ushort4*)&dst[(size_t)np * 1536 + kb + 4] = *(ushort4*)&out[4];
}

// ---------------- bf16 MFMA GEMM: 128x128 tile, BK=64, 4 waves ----------
template<int MODE>
__global__ __launch_bounds__(256)
void mgemm(const u16* __restrict__ A, const u16* __restrict__ Bt,
           float* __restrict__ C0, float* __restrict__ C1, float* __restrict__ C2) {
    __shared__ u16 As[128 * 64];
    __shared__ u16 Bs[128 * 64];

    const int tid = threadIdx.x;
    const int l = tid & 63, wid = tid >> 6;
    const int m0 = blockIdx.y * 128;
    const int n0 = blockIdx.x * 128;
    const int wm = (wid >> 1) * 64, wn = (wid & 1) * 64;
    const int fr = l & 15, fk = l >> 4;
    const int srow = l >> 3, slot = l & 7;

    f32x4 acc[4][4];
#pragma unroll
    for (int m = 0; m < 4; ++m)
#pragma unroll
        for (int n = 0; n < 4; ++n) acc[m][n] = (f32x4){0.f, 0.f, 0.f, 0.f};

    for (int kt = 0; kt < 24; ++kt) {
        const int k0 = kt * 64;
        const int k0A = (k0 >= 1024) ? (k0 - 1024) : k0;
#pragma unroll
        for (int j = 0; j < 4; ++j) {
            const int r = wid * 32 + j * 8 + srow;
            const int cA = (slot ^ (r & 7)) * 8;       // pre-swizzled source
            const u16* gA = A + (size_t)(m0 + r) * 1024 + k0A + cA;
            __builtin_amdgcn_global_load_lds(
                (const __attribute__((address_space(1))) unsigned int*)gA,
                (__attribute__((address_space(3))) unsigned int*)(As + wid * 2048 + j * 512),
                16, 0, 0);
            const u16* gB = Bt + (size_t)(n0 + r) * 1536 + k0 + cA;
            __builtin_amdgcn_global_load_lds(
                (const __attribute__((address_space(1))) unsigned int*)gB,
                (__attribute__((address_space(3))) unsigned int*)(Bs + wid * 2048 + j * 512),
                16, 0, 0);
        }
        asm volatile("s_waitcnt vmcnt(0)" ::: "memory");
        __syncthreads();

        bf16x8 af[4][2], bfr[4][2];
#pragma unroll
        for (int m = 0; m < 4; ++m) {
            const int row = wm + m * 16 + fr;
#pragma unroll
            for (int kk = 0; kk < 2; ++kk) {
                const int b = (kk * 64 + fk * 16) ^ ((row & 7) << 4);   // swz read
                af[m][kk] = *(const bf16x8*)((const char*)As + row * 128 + b);
            }
        }
#pragma unroll
        for (int n = 0; n < 4; ++n) {
            const int row = wn + n * 16 + fr;
#pragma unroll
            for (int kk = 0; kk < 2; ++kk) {
                const int b = (kk * 64 + fk * 16) ^ ((row & 7) << 4);
                bfr[n][kk] = *(const bf16x8*)((const char*)Bs + row * 128 + b);
            }
        }
#pragma unroll
        for (int kk = 0; kk < 2; ++kk)
#pragma unroll
            for (int m = 0; m < 4; ++m)
#pragma unroll
                for (int n = 0; n < 4; ++n)
                    acc[m][n] = __builtin_amdgcn_mfma_f32_16x16x32_bf16(
                        af[m][kk], bfr[n][kk], acc[m][n], 0, 0, 0);
        __syncthreads();
    }

    if (MODE == 0) {
#pragma unroll
        for (int nf = 0; nf < 4; ++nf) {
            const int ccol = n0 + wn + nf * 16 + fr;
            const int t = ccol >> 9;
            const int h = (ccol >> 6) & 7;
            const int d = ccol & 63;
            float* Cp = (t == 0) ? C0 : (t == 1) ? C1 : C2;
#pragma unroll
            for (int mf = 0; mf < 4; ++mf) {
#pragma unroll
                for (int i = 0; i < 4; ++i) {
                    const int grow = m0 + wm + mf * 16 + fk * 4 + i;
                    const int b_ = grow / NNODE;
                    const int nn = grow - b_ * NNODE;
                    Cp[((size_t)((b_ * NHEAD + h) * NNODE + nn)) * 64 + d] = acc[mf][nf][i];
                }
            }
        }
    } else {
#pragma unroll
        for (int nf = 0; nf < 4; ++nf) {
            const int ccol = n0 + wn + nf * 16 + fr;
#pragma unroll
            for (int mf = 0; mf < 4; ++mf) {
#pragma unroll
                for (int i = 0; i < 4; ++i) {
                    const int grow = m0 + wm + mf * 16 + fk * 4 + i;
                    C0[(size_t)grow * 512 + ccol] = acc[mf][nf][i];
                }
            }
        }
    }
}

// ------------- absolute-position RoPE pre-rotation of Q and K (in-place) ----
__global__ void rot_qk(float* __restrict__ Qf, float* __restrict__ Kf,
                       const float* __restrict__ freqs) {
    int id = blockIdx.x * 256 + threadIdx.x;          // 16*2304*8
    if (id >= 16 * NNODE * 8) return;
    const int p4 = id & 7;                            // group of 4 pairs
    const int node = id >> 3;                         // bh*2304 + n
    const int h = (node / NNODE) & 7;
    const int n = node % NNODE;
    const float r = (float)(n / WGRID), c = (float)(n % WGRID);

    const size_t base = (size_t)node * 64 + p4 * 8;
    float4 qa = *(float4*)&Qf[base], qb = *(float4*)&Qf[base + 4];
    float4 ka = *(float4*)&Kf[base], kb = *(float4*)&Kf[base + 4];

    const int pb = p4 * 4;
    float cs[4], sn[4];
#pragma unroll
    for (int j = 0; j < 4; ++j) {
        float th = r * freqs[h * 64 + pb + j] + c * freqs[h * 64 + 32 + pb + j];
        __sincosf(th, &sn[j], &cs[j]);
    }
    float4 qo, ko;
    qo.x = qa.x * cs[0] - qa.y * sn[0];  qo.y = qa.x * sn[0] + qa.y * cs[0];
    qo.z = qa.z * cs[1] - qa.w * sn[1];  qo.w = qa.z * sn[1] + qa.w * cs[1];
    *(float4*)&Qf[base] = qo;
    qo.x = qb.x * cs[2] - qb.y * sn[2];  qo.y = qb.x * sn[2] + qb.y * cs[2];
    qo.z = qb.z * cs[3] - qb.w * sn[3];  qo.w = qb.z * sn[3] + qb.w * cs[3];
    *(float4*)&Qf[base + 4] = qo;
    ko.x = ka.x * cs[0] - ka.y * sn[0];  ko.y = ka.x * sn[0] + ka.y * cs[0];
    ko.z = ka.z * cs[1] - ka.w * sn[1];  ko.w = ka.z * sn[1] + ka.w * cs[1];
    *(float4*)&Kf[base] = ko;
    ko.x = kb.x * cs[2] - kb.y * sn[2];  ko.y = kb.x * sn[2] + kb.y * cs[2];
    ko.z = kb.z * cs[3] - kb.w * sn[3];  ko.w = kb.z * sn[3] + kb.w * cs[3];
    *(float4*)&Kf[base + 4] = ko;
}

// ---------------- attention v3: 4x8 query tile, LDS-staged K/V halo --------
// Block = 256 thr (4 waves). Wave wid owns grid row r0+wid, 8 queries.
// Score: lane=(qs,wg) -> 6-7 neighbors each, full 64-d fp32 dot from LDS.
// PV: lane=(qs,dg) -> 8 dims, weight broadcast from LDS.
__global__ __launch_bounds__(256)
void attn3(const float* __restrict__ Qr, const float* __restrict__ Kr,
           const float* __restrict__ Vf, u16* __restrict__ out2) {
    __shared__ float2 Ks[140 * 33];
    __shared__ float2 Vs[140 * 33];
    __shared__ float  PW[32 * 50];

    const int tid = threadIdx.x;
    const int wid = tid >> 6, lane = tid & 63;
    const int qs = lane >> 3, wg = lane & 7;       // wg doubles as dg in PV

    const int bid = blockIdx.x;
    const int t  = bid % 72, bh = bid / 72;
    const int tr = t % 12,   tc = t / 12;
    const int r0 = tr * 4,   c0 = tc * 8;
    const int h  = bh & 7,   b_ = bh >> 3;

    const int lr0 = max(0, r0 - 3), lr1 = min(HGRID - 1, r0 + 6);
    const int lc0 = max(0, c0 - 3), lc1 = min(WGRID - 1, c0 + 10);
    const int NR = lr1 - lr0 + 1, NC = lc1 - lc0 + 1;

    const float* Kb = Kr + (size_t)bh * NNODE * 64;
    const float* Vb = Vf + (size_t)bh * NNODE * 64;

    // q row into registers (same for the 8 lanes sharing qs -> L1 dedup)
    const int rq = r0 + wid, cq = c0 + qs;
    const int nq = rq * WGRID + cq;
    const float* qrow = Qr + (size_t)bh * NNODE * 64 + (size_t)nq * 64;
    float2 q2[32];
#pragma unroll
    for (int j = 0; j < 16; ++j) {
        float4 v = *(const float4*)&qrow[j * 4];
        q2[2 * j]     = make_float2(v.x, v.y);
        q2[2 * j + 1] = make_float2(v.z, v.w);
    }

    // ---- stage K,V halo (coalesced: rows are runs of consecutive n) ----
    const int cnt = NR * NC * 16;
    for (int i = tid; i < cnt; i += 256) {
        const int row = i >> 4, c4 = (i & 15) << 2;
        const int glr = row / NC, glc = row - glr * NC;
        const int n = (lr0 + glr) * WGRID + (lc0 + glc);
        float4 kv = *(const float4*)&Kb[(size_t)n * 64 + c4];
        float4 vv = *(const float4*)&Vb[(size_t)n * 64 + c4];
        Ks[row * 33 + (c4 >> 1)]     = make_float2(kv.x, kv.y);
        Ks[row * 33 + (c4 >> 1) + 1] = make_float2(kv.z, kv.w);
        Vs[row * 33 + (c4 >> 1)]     = make_float2(vv.x, vv.y);
        Vs[row * 33 + (c4 >> 1) + 1] = make_float2(vv.z, vv.w);
    }
    __syncthreads();

    // ---- score phase ----
    float sc[7];
    float mx = -1e30f;
#pragma unroll
    for (int k = 0; k < 7; ++k) {
        const int w = wg + 8 * k;
        sc[k] = -1e30f;
        if (w < WSZ) {
            const int dr = w / 7 - RAD, dc = w % 7 - RAD;
            const int nr = rq + dr, nc = cq + dc;
            const bool valid = ((unsigned)nr < (unsigned)HGRID) &&
                               ((unsigned)nc < (unsigned)WGRID);
            const int nrl = min(max(nr, lr0), lr1) - lr0;
            const int ncl = min(max(nc, lc0), lc1) - lc0;
            const float2* kp = &Ks[(nrl * NC + ncl) * 33];
            float s = 0.0f;
#pragma unroll
            for (int j = 0; j < 32; ++j) {
                float2 k2 = kp[j];
                s = fmaf(q2[j].x, k2.x, s);
                s = fmaf(q2[j].y, k2.y, s);
            }
            sc[k] = valid ? s * SCALE : -1e9f;
            mx = fmaxf(mx, sc[k]);
        }
    }
#pragma unroll
    for (int o = 1; o < 8; o <<= 1) mx = fmaxf(mx, __shfl_xor(mx, o));
    float es[7], sum = 0.0f;
#pragma unroll
    for (int k = 0; k < 7; ++k) {
        const int w = wg + 8 * k;
        if (w < WSZ) { es[k] = __expf(sc[k] - mx); sum += es[k]; }
    }
#pragma unroll
    for (int o = 1; o < 8; o <<= 1) sum += __shfl_xor(sum, o);
    const float inv = 1.0f / sum;
    const int q = wid * 8 + qs;
#pragma unroll
    for (int k = 0; k < 7; ++k) {
        const int w = wg + 8 * k;
        if (w < WSZ) PW[q * 50 + w] = es[k] * inv;
    }
    __syncthreads();

    // ---- PV phase: lane=(qs,dg) accumulates 8 dims ----
    const int dg = wg;
    float2 acc[4] = {{0,0},{0,0},{0,0},{0,0}};
#pragma unroll
    for (int w = 0; w < WSZ; ++w) {
        const int dr = w / 7 - RAD, dc = w % 7 - RAD;
        const int nr = rq + dr, nc = cq + dc;
        const int nrl = min(max(nr, lr0), lr1) - lr0;
        const int ncl = min(max(nc, lc0), lc1) - lc0;
        const float pw = PW[q * 50 + w];                 // 8-lane broadcast
        const float2* vp = &Vs[(nrl * NC + ncl) * 33 + dg * 4];
#pragma unroll
        for (int j = 0; j < 4; ++j) {
            float2 v2 = vp[j];
            acc[j].x = fmaf(pw, v2.x, acc[j].x);
            acc[j].y = fmaf(pw, v2.y, acc[j].y);
        }
    }

    // ---- write hi/lo bf16 into x2 row for the W_O GEMM ----
    float vals[8] = {acc[0].x, acc[0].y, acc[1].x, acc[1].y,
                     acc[2].x, acc[2].y, acc[3].x, acc[3].y};
    ushort4 hi0, hi1, lo0, lo1;
    hi0.x = f2bf(vals[0]); lo0.x = f2bf(vals[0] - bf2f(hi0.x));
    hi0.y = f2bf(vals[1]); lo0.y = f2bf(vals[1] - bf2f(hi0.y));
    hi0.z = f2bf(vals[2]); lo0.z = f2bf(vals[2] - bf2f(hi0.z));
    hi0.w = f2bf(vals[3]); lo0.w = f2bf(vals[3] - bf2f(hi0.w));
    hi1.x = f2bf(vals[4]); lo1.x = f2bf(vals[4] - bf2f(hi1.x));
    hi1.y = f2bf(vals[5]); lo1.y = f2bf(vals[5] - bf2f(hi1.y));
    hi1.z = f2bf(vals[6]); lo1.z = f2bf(vals[6] - bf2f(hi1.z));
    hi1.w = f2bf(vals[7]); lo1.w = f2bf(vals[7] - bf2f(hi1.w));
    const size_t rowb = (size_t)(b_ * NNODE + nq) * 1024 + h * 64 + dg * 8;
    *(ushort4*)&out2[rowb]           = hi0;
    *(ushort4*)&out2[rowb + 4]       = hi1;
    *(ushort4*)&out2[rowb + 512]     = lo0;
    *(ushort4*)&out2[rowb + 512 + 4] = lo1;
}

extern "C" void kernel_launch(void* const* d_in, const int* in_sizes, int n_in,
                              void* d_out, int out_size, void* d_ws, size_t ws_size,
                              hipStream_t stream) {
    const float* x     = (const float*)d_in[0];
    const float* WQ    = (const float*)d_in[2];
    const float* WK    = (const float*)d_in[3];
    const float* WV    = (const float*)d_in[4];
    const float* WO    = (const float*)d_in[5];
    const float* freqs = (const float*)d_in[7];

    float* Qf  = (float*)d_ws;
    float* Kf  = Qf + TEN;
    float* Vf  = Kf + TEN;
    u16*   x2  = (u16*)(Vf + TEN);                 // MROWS x 1024
    u16*   Wq2 = x2 + (size_t)MROWS * 1024;        // 1536 x 1536
    u16*   Wo2 = Wq2 + (size_t)1536 * 1536;        // 512 x 1536

    conv_x<<<(MROWS * 128 + 255) / 256, 256, 0, stream>>>(x, x2);
    conv_w<1536><<<(1536 * 192 + 255) / 256, 256, 0, stream>>>(WQ, WK, WV, Wq2);
    conv_w<512><<<(512 * 192 + 255) / 256, 256, 0, stream>>>(WO, WO, WO, Wo2);

    dim3 gqkv(12, 36);
    mgemm<0><<<gqkv, 256, 0, stream>>>(x2, Wq2, Qf, Kf, Vf);

    rot_qk<<<(16 * NNODE * 8) / 256, 256, 0, stream>>>(Qf, Kf, freqs);

    attn3<<<16 * 72, 256, 0, stream>>>(Qf, Kf, Vf, x2);

    dim3 go(4, 36);
    mgemm<1><<<go, 256, 0, stream>>>(x2, Wo2, (float*)d_out, nullptr, nullptr);
}

// Round 5
// 127.845 us; speedup vs baseline: 3.0118x; 1.1566x over previous
//
#include <hip/hip_runtime.h>
#include <math.h>

// RelativePositionAttention on MI355X (gfx950)
//
// Algebraic simplifications (verified rounds 1-4, absmax 3.9e-3):
//  - U_ortho @ U_ortho^T == I -> skip QR projection entirely.
//  - RoPE factorizes: pre-rotate Q,K by ABSOLUTE position; attention becomes
//    plain masked sliding-window attention. Rotation fused into attn staging.
//  - GEMMs: bf16 MFMA hi/lo split-K (K=1536) as one GEMM, m97 structure.
//
// Round 5: attn4 = single 37KB LDS buffer time-shared K->V (4 blocks/CU vs 1),
// transposed [dpair][row] layout with odd stride 145 (conflict-free score,
// exact-2-way PV), RoPE fused into staging (rot_qk kernel deleted), softmax
// weights broadcast by shuffle (PW buffer deleted).

#define BB 2
#define HGRID 48
#define WGRID 48
#define NNODE (HGRID*WGRID)   // 2304
#define RAD 3
#define WSZ 49
#define DMODEL 512
#define NHEAD 8
#define SCALE 0.125f
#define MROWS (BB*NNODE)      // 4608
#define TEN ((size_t)MROWS*DMODEL)
#define TSTRIDE 145           // float2 units; odd -> dpair stride = 2 banks

typedef unsigned short u16;
typedef __attribute__((ext_vector_type(8))) short bf16x8;
typedef __attribute__((ext_vector_type(4))) float f32x4;

__device__ __forceinline__ u16 f2bf(float f) {
    unsigned u = __float_as_uint(f);
    return (u16)((u + 0x7FFFu + ((u >> 16) & 1u)) >> 16);
}
__device__ __forceinline__ float bf2f(u16 s) {
    return __uint_as_float(((unsigned)s) << 16);
}

// ---------------- x -> [hi | lo] bf16, row width 1024 ----------------
__global__ void conv_x(const float* __restrict__ x, u16* __restrict__ x2) {
    int id = blockIdx.x * 256 + threadIdx.x;         // MROWS*128
    if (id >= MROWS * 128) return;
    int r = id >> 7, c4 = (id & 127) << 2;
    float4 v = *(const float4*)&x[(size_t)r * 512 + c4];
    ushort4 hi, lo;
    hi.x = f2bf(v.x); lo.x = f2bf(v.x - bf2f(hi.x));
    hi.y = f2bf(v.y); lo.y = f2bf(v.y - bf2f(hi.y));
    hi.z = f2bf(v.z); lo.z = f2bf(v.z - bf2f(hi.z));
    hi.w = f2bf(v.w); lo.w = f2bf(v.w - bf2f(hi.w));
    *(ushort4*)&x2[(size_t)r * 1024 + c4]       = hi;
    *(ushort4*)&x2[(size_t)r * 1024 + 512 + c4] = lo;
}

// ------- W (512 x 512 row-major) -> B'^T [n'][k'=0..1535] --------
template<int NW>
__global__ void conv_w(const float* __restrict__ S0, const float* __restrict__ S1,
                       const float* __restrict__ S2, u16* __restrict__ dst) {
    int id = blockIdx.x * 256 + threadIdx.x;         // NW*192
    if (id >= NW * 192) return;
    int np = id % NW;
    int kb = (id / NW) * 8;
    const float* S = S0;
    int n = np;
    if (NW == 1536) { int t = np >> 9; n = np & 511; S = (t==0)?S0:(t==1)?S1:S2; }
    u16 out[8];
#pragma unroll
    for (int i = 0; i < 8; ++i) {
        int kp = kb + i;
        int kf = kp & 511;
        float wv = S[(size_t)kf * 512 + n];
        u16 h = f2bf(wv);
        out[i] = (kp < 1024) ? h : f2bf(wv - bf2f(h));
    }
    *(ushort4*)&dst[(size_t)np * 1536 + kb]     = *(ushort4*)&out[0];
    *(ushort4*)&dst[(size_t)np * 1536 + kb + 4] = *(ushort4*)&out[4];
}

// ---------------- bf16 MFMA GEMM: 128x128 tile, BK=64, 4 waves ----------
template<int MODE>
__global__ __launch_bounds__(256)
void mgemm(const u16* __restrict__ A, const u16* __restrict__ Bt,
           float* __restrict__ C0, float* __restrict__ C1, float* __restrict__ C2) {
    __shared__ u16 As[128 * 64];
    __shared__ u16 Bs[128 * 64];

    const int tid = threadIdx.x;
    const int l = tid & 63, wid = tid >> 6;
    const int m0 = blockIdx.y * 128;
    const int n0 = blockIdx.x * 128;
    const int wm = (wid >> 1) * 64, wn = (wid & 1) * 64;
    const int fr = l & 15, fk = l >> 4;
    const int srow = l >> 3, slot = l & 7;

    f32x4 acc[4][4];
#pragma unroll
    for (int m = 0; m < 4; ++m)
#pragma unroll
        for (int n = 0; n < 4; ++n) acc[m][n] = (f32x4){0.f, 0.f, 0.f, 0.f};

    for (int kt = 0; kt < 24; ++kt) {
        const int k0 = kt * 64;
        const int k0A = (k0 >= 1024) ? (k0 - 1024) : k0;
#pragma unroll
        for (int j = 0; j < 4; ++j) {
            const int r = wid * 32 + j * 8 + srow;
            const int cA = (slot ^ (r & 7)) * 8;       // pre-swizzled source
            const u16* gA = A + (size_t)(m0 + r) * 1024 + k0A + cA;
            __builtin_amdgcn_global_load_lds(
                (const __attribute__((address_space(1))) unsigned int*)gA,
                (__attribute__((address_space(3))) unsigned int*)(As + wid * 2048 + j * 512),
                16, 0, 0);
            const u16* gB = Bt + (size_t)(n0 + r) * 1536 + k0 + cA;
            __builtin_amdgcn_global_load_lds(
                (const __attribute__((address_space(1))) unsigned int*)gB,
                (__attribute__((address_space(3))) unsigned int*)(Bs + wid * 2048 + j * 512),
                16, 0, 0);
        }
        asm volatile("s_waitcnt vmcnt(0)" ::: "memory");
        __syncthreads();

        bf16x8 af[4][2], bfr[4][2];
#pragma unroll
        for (int m = 0; m < 4; ++m) {
            const int row = wm + m * 16 + fr;
#pragma unroll
            for (int kk = 0; kk < 2; ++kk) {
                const int b = (kk * 64 + fk * 16) ^ ((row & 7) << 4);   // swz read
                af[m][kk] = *(const bf16x8*)((const char*)As + row * 128 + b);
            }
        }
#pragma unroll
        for (int n = 0; n < 4; ++n) {
            const int row = wn + n * 16 + fr;
#pragma unroll
            for (int kk = 0; kk < 2; ++kk) {
                const int b = (kk * 64 + fk * 16) ^ ((row & 7) << 4);
                bfr[n][kk] = *(const bf16x8*)((const char*)Bs + row * 128 + b);
            }
        }
#pragma unroll
        for (int kk = 0; kk < 2; ++kk)
#pragma unroll
            for (int m = 0; m < 4; ++m)
#pragma unroll
                for (int n = 0; n < 4; ++n)
                    acc[m][n] = __builtin_amdgcn_mfma_f32_16x16x32_bf16(
                        af[m][kk], bfr[n][kk], acc[m][n], 0, 0, 0);
        __syncthreads();
    }

    if (MODE == 0) {
#pragma unroll
        for (int nf = 0; nf < 4; ++nf) {
            const int ccol = n0 + wn + nf * 16 + fr;
            const int t = ccol >> 9;
            const int h = (ccol >> 6) & 7;
            const int d = ccol & 63;
            float* Cp = (t == 0) ? C0 : (t == 1) ? C1 : C2;
#pragma unroll
            for (int mf = 0; mf < 4; ++mf) {
#pragma unroll
                for (int i = 0; i < 4; ++i) {
                    const int grow = m0 + wm + mf * 16 + fk * 4 + i;
                    const int b_ = grow / NNODE;
                    const int nn = grow - b_ * NNODE;
                    Cp[((size_t)((b_ * NHEAD + h) * NNODE + nn)) * 64 + d] = acc[mf][nf][i];
                }
            }
        }
    } else {
#pragma unroll
        for (int nf = 0; nf < 4; ++nf) {
            const int ccol = n0 + wn + nf * 16 + fr;
#pragma unroll
            for (int mf = 0; mf < 4; ++mf) {
#pragma unroll
                for (int i = 0; i < 4; ++i) {
                    const int grow = m0 + wm + mf * 16 + fk * 4 + i;
                    C0[(size_t)grow * 512 + ccol] = acc[mf][nf][i];
                }
            }
        }
    }
}

// ---------------- attention v4 ----------------
// Block = 256 thr (4 waves), 4x8 query tile for one (b,h). One 37KB LDS
// buffer T time-shared: rotated-K (transposed [dpair][row], stride 145) for
// scores, then V for PV. RoPE by absolute position fused into staging.
__global__ __launch_bounds__(256, 4)
void attn4(const float* __restrict__ Qf, const float* __restrict__ Kf,
           const float* __restrict__ Vf, const float* __restrict__ freqs,
           u16* __restrict__ out2) {
    __shared__ float2 T[32 * TSTRIDE];

    const int tid = threadIdx.x;
    const int wid = tid >> 6, lane = tid & 63;
    const int qs = lane >> 3, wg = lane & 7;

    const int bid = blockIdx.x;
    const int t  = bid % 72, bh = bid / 72;
    const int tr = t % 12,   tc = t / 12;
    const int r0 = tr * 4,   c0 = tc * 8;
    const int h  = bh & 7,   b_ = bh >> 3;

    const int lr0 = max(0, r0 - 3), lr1 = min(HGRID - 1, r0 + 6);
    const int lc0 = max(0, c0 - 3), lc1 = min(WGRID - 1, c0 + 10);
    const int NR = lr1 - lr0 + 1, NC = lc1 - lc0 + 1;

    const float* Kb = Kf + (size_t)bh * NNODE * 64;
    const float* Vb = Vf + (size_t)bh * NNODE * 64;
    const float* fr_ = freqs + h * 64;
    const float* fc_ = freqs + h * 64 + 32;

    // ---- load + rotate Q row into registers (8 lanes share a row; L1 dedup)
    const int rq = r0 + wid, cq = c0 + qs;
    const int nq = rq * WGRID + cq;
    const float* qrow = Qf + (size_t)bh * NNODE * 64 + (size_t)nq * 64;
    float2 q2[32];
    {
        const float rfq = (float)rq, cfq = (float)cq;
#pragma unroll
        for (int j = 0; j < 16; ++j) {
            float4 v = *(const float4*)&qrow[j * 4];
            float th0 = rfq * fr_[2 * j]     + cfq * fc_[2 * j];
            float th1 = rfq * fr_[2 * j + 1] + cfq * fc_[2 * j + 1];
            float s0, c0v, s1, c1v;
            __sincosf(th0, &s0, &c0v);
            __sincosf(th1, &s1, &c1v);
            q2[2 * j]     = make_float2(v.x * c0v - v.y * s0, v.x * s0 + v.y * c0v);
            q2[2 * j + 1] = make_float2(v.z * c1v - v.w * s1, v.z * s1 + v.w * c1v);
        }
    }

    // ---- stage rotated K transposed: T[p*145 + row] ----
    const int cnt = NR * NC * 16;                    // one float4 (2 pairs) each
    for (int i = tid; i < cnt; i += 256) {
        const int row = i >> 4, p2 = i & 15;
        const int glr = row / NC, glc = row - glr * NC;
        const int rn = lr0 + glr, cn = lc0 + glc;
        const int n = rn * WGRID + cn;
        float4 v = *(const float4*)&Kb[(size_t)n * 64 + p2 * 4];
        const float rf = (float)rn, cf = (float)cn;
        const int p0 = 2 * p2;
        float th0 = rf * fr_[p0]     + cf * fc_[p0];
        float th1 = rf * fr_[p0 + 1] + cf * fc_[p0 + 1];
        float s0, c0v, s1, c1v;
        __sincosf(th0, &s0, &c0v);
        __sincosf(th1, &s1, &c1v);
        T[p0 * TSTRIDE + row]       = make_float2(v.x * c0v - v.y * s0, v.x * s0 + v.y * c0v);
        T[(p0 + 1) * TSTRIDE + row] = make_float2(v.z * c1v - v.w * s1, v.z * s1 + v.w * c1v);
    }
    __syncthreads();

    // ---- score phase: lane (qs,wg) -> neighbors w = wg + 8k ----
    float sc[7], es[7];
    float mx = -1e30f;
#pragma unroll
    for (int k = 0; k < 7; ++k) {
        const int w = wg + 8 * k;
        sc[k] = -1e30f;
        if (w < WSZ) {
            const int dr = w / 7 - RAD, dc = w % 7 - RAD;
            const int nr = rq + dr, nc = cq + dc;
            const bool valid = ((unsigned)nr < (unsigned)HGRID) &&
                               ((unsigned)nc < (unsigned)WGRID);
            const int nrl = min(max(nr, lr0), lr1) - lr0;
            const int ncl = min(max(nc, lc0), lc1) - lc0;
            const int row = nrl * NC + ncl;
            float s = 0.0f;
#pragma unroll
            for (int j = 0; j < 32; ++j) {
                float2 k2 = T[j * TSTRIDE + row];
                s = fmaf(q2[j].x, k2.x, s);
                s = fmaf(q2[j].y, k2.y, s);
            }
            sc[k] = valid ? s * SCALE : -1e9f;
            mx = fmaxf(mx, sc[k]);
        }
    }
#pragma unroll
    for (int o = 1; o < 8; o <<= 1) mx = fmaxf(mx, __shfl_xor(mx, o));
    float sum = 0.0f;
#pragma unroll
    for (int k = 0; k < 7; ++k) {
        const int w = wg + 8 * k;
        es[k] = 0.0f;
        if (w < WSZ) { es[k] = __expf(sc[k] - mx); sum += es[k]; }
    }
#pragma unroll
    for (int o = 1; o < 8; o <<= 1) sum += __shfl_xor(sum, o);
    const float inv = 1.0f / sum;
    float esn[7];
#pragma unroll
    for (int k = 0; k < 7; ++k) esn[k] = es[k] * inv;

    __syncthreads();   // all waves done reading K

    // ---- stage V (no rotation), same transposed layout ----
    for (int i = tid; i < cnt; i += 256) {
        const int row = i >> 4, p2 = i & 15;
        const int glr = row / NC, glc = row - glr * NC;
        const int n = (lr0 + glr) * WGRID + (lc0 + glc);
        float4 v = *(const float4*)&Vb[(size_t)n * 64 + p2 * 4];
        T[(2 * p2) * TSTRIDE + row]     = make_float2(v.x, v.y);
        T[(2 * p2 + 1) * TSTRIDE + row] = make_float2(v.z, v.w);
    }
    __syncthreads();

    // ---- PV phase: lane (qs,dg) accumulates 8 dims for q=(rq, c0+qs) ----
    const int dg = wg;
    float2 acc[4] = {{0, 0}, {0, 0}, {0, 0}, {0, 0}};
#pragma unroll
    for (int w = 0; w < WSZ; ++w) {
        const int dr = w / 7 - RAD, dc = w % 7 - RAD;
        const int nr = rq + dr, nc = cq + dc;
        const int nrl = min(max(nr, lr0), lr1) - lr0;
        const int ncl = min(max(nc, lc0), lc1) - lc0;
        const int row = nrl * NC + ncl;
        const float pw = __shfl(esn[w >> 3], (lane & 0x38) | (w & 7));
#pragma unroll
        for (int j = 0; j < 4; ++j) {
            float2 v2 = T[(dg * 4 + j) * TSTRIDE + row];
            acc[j].x = fmaf(pw, v2.x, acc[j].x);
            acc[j].y = fmaf(pw, v2.y, acc[j].y);
        }
    }

    // ---- write hi/lo bf16 into x2 row for the W_O GEMM ----
    float vals[8] = {acc[0].x, acc[0].y, acc[1].x, acc[1].y,
                     acc[2].x, acc[2].y, acc[3].x, acc[3].y};
    ushort4 hi0, hi1, lo0, lo1;
    hi0.x = f2bf(vals[0]); lo0.x = f2bf(vals[0] - bf2f(hi0.x));
    hi0.y = f2bf(vals[1]); lo0.y = f2bf(vals[1] - bf2f(hi0.y));
    hi0.z = f2bf(vals[2]); lo0.z = f2bf(vals[2] - bf2f(hi0.z));
    hi0.w = f2bf(vals[3]); lo0.w = f2bf(vals[3] - bf2f(hi0.w));
    hi1.x = f2bf(vals[4]); lo1.x = f2bf(vals[4] - bf2f(hi1.x));
    hi1.y = f2bf(vals[5]); lo1.y = f2bf(vals[5] - bf2f(hi1.y));
    hi1.z = f2bf(vals[6]); lo1.z = f2bf(vals[6] - bf2f(hi1.z));
    hi1.w = f2bf(vals[7]); lo1.w = f2bf(vals[7] - bf2f(hi1.w));
    const size_t rowb = (size_t)(b_ * NNODE + nq) * 1024 + h * 64 + dg * 8;
    *(ushort4*)&out2[rowb]           = hi0;
    *(ushort4*)&out2[rowb + 4]       = hi1;
    *(ushort4*)&out2[rowb + 512]     = lo0;
    *(ushort4*)&out2[rowb + 512 + 4] = lo1;
}

extern "C" void kernel_launch(void* const* d_in, const int* in_sizes, int n_in,
                              void* d_out, int out_size, void* d_ws, size_t ws_size,
                              hipStream_t stream) {
    const float* x     = (const float*)d_in[0];
    const float* WQ    = (const float*)d_in[2];
    const float* WK    = (const float*)d_in[3];
    const float* WV    = (const float*)d_in[4];
    const float* WO    = (const float*)d_in[5];
    const float* freqs = (const float*)d_in[7];

    float* Qf  = (float*)d_ws;
    float* Kf  = Qf + TEN;
    float* Vf  = Kf + TEN;
    u16*   x2  = (u16*)(Vf + TEN);                 // MROWS x 1024
    u16*   Wq2 = x2 + (size_t)MROWS * 1024;        // 1536 x 1536
    u16*   Wo2 = Wq2 + (size_t)1536 * 1536;        // 512 x 1536

    conv_x<<<(MROWS * 128 + 255) / 256, 256, 0, stream>>>(x, x2);
    conv_w<1536><<<(1536 * 192 + 255) / 256, 256, 0, stream>>>(WQ, WK, WV, Wq2);
    conv_w<512><<<(512 * 192 + 255) / 256, 256, 0, stream>>>(WO, WO, WO, Wo2);

    dim3 gqkv(12, 36);
    mgemm<0><<<gqkv, 256, 0, stream>>>(x2, Wq2, Qf, Kf, Vf);

    attn4<<<16 * 72, 256, 0, stream>>>(Qf, Kf, Vf, freqs, x2);

    dim3 go(4, 36);
    mgemm<1><<<go, 256, 0, stream>>>(x2, Wo2, (float*)d_out, nullptr, nullptr);
}

// Round 6
// 80.498 us; speedup vs baseline: 4.7832x; 1.5882x over previous
//
#include <hip/hip_runtime.h>
#include <math.h>

// RelativePositionAttention on MI355X (gfx950)
//
// Algebraic simplifications (verified rounds 1-5, absmax <= 7.8e-3):
//  - U_ortho @ U_ortho^T == I -> skip QR projection entirely.
//  - RoPE factorizes: pre-rotate Q,K by ABSOLUTE position; attention becomes
//    plain masked sliding-window attention. Rotation fused into attn staging.
//  - GEMMs on the matrix pipe; attention fp32 VALU from LDS.
//
// Round 6: GEMMs switched from hi/lo-split bf16 (K=1536) to single-pass fp16
// (K=512): 3x fewer MFMA FLOPs and staging bytes. fp16 rounding adds ~7e-4
// absolute error (threshold 3.16e-2). Weight conversion unified to one kernel.

#define BB 2
#define HGRID 48
#define WGRID 48
#define NNODE (HGRID*WGRID)   // 2304
#define RAD 3
#define WSZ 49
#define DMODEL 512
#define NHEAD 8
#define SCALE 0.125f
#define MROWS (BB*NNODE)      // 4608
#define TEN ((size_t)MROWS*DMODEL)
#define TSTRIDE 145           // float2 units; odd -> dpair stride = 2 banks

typedef unsigned short u16;
typedef _Float16 f16;
typedef __attribute__((ext_vector_type(8))) _Float16 f16x8;
typedef __attribute__((ext_vector_type(4))) float f32x4;

// ---------------- x (fp32, 512-wide) -> fp16 ----------------
__global__ void conv_x(const float* __restrict__ x, f16* __restrict__ x2) {
    int id = blockIdx.x * 256 + threadIdx.x;         // MROWS*64
    if (id >= MROWS * 64) return;
    int r = id >> 6, c8 = (id & 63) << 3;
    float4 a = *(const float4*)&x[(size_t)r * 512 + c8];
    float4 b = *(const float4*)&x[(size_t)r * 512 + c8 + 4];
    f16 o[8] = {(f16)a.x, (f16)a.y, (f16)a.z, (f16)a.w,
                (f16)b.x, (f16)b.y, (f16)b.z, (f16)b.w};
    *(f16x8*)&x2[(size_t)r * 512 + c8] = *(f16x8*)o;
}

// ---- all weights -> fp16 B^T [n'][k], n' in [0,2048): QKV rows then W_O ----
__global__ void conv_w(const float* __restrict__ WQ, const float* __restrict__ WK,
                       const float* __restrict__ WV, const float* __restrict__ WO,
                       f16* __restrict__ dst) {
    int id = blockIdx.x * 256 + threadIdx.x;         // 2048*64
    if (id >= 2048 * 64) return;
    int np = id >> 6;
    int kb = (id & 63) << 3;
    const float* S;
    int n;
    if (np < 1536) { int t = np >> 9; n = np & 511; S = (t == 0) ? WQ : (t == 1) ? WK : WV; }
    else           { n = np - 1536;  S = WO; }
    f16 o[8];
#pragma unroll
    for (int i = 0; i < 8; ++i) o[i] = (f16)S[(size_t)(kb + i) * 512 + n];
    *(f16x8*)&dst[(size_t)np * 512 + kb] = *(f16x8*)o;
}

// ---------------- fp16 MFMA GEMM: 128x128 tile, BK=64, K=512, 4 waves ------
// A: M x 512 fp16 row-major. Bt: NB x 512 fp16 (pre-transposed).
// MODE 0: NB=1536, scatter C -> Qf/Kf/Vf (bh,n,d) fp32. MODE 1: NB=512 row-major.
template<int MODE>
__global__ __launch_bounds__(256)
void mgemm(const f16* __restrict__ A, const f16* __restrict__ Bt,
           float* __restrict__ C0, float* __restrict__ C1, float* __restrict__ C2) {
    __shared__ f16 As[128 * 64];
    __shared__ f16 Bs[128 * 64];

    const int tid = threadIdx.x;
    const int l = tid & 63, wid = tid >> 6;
    const int m0 = blockIdx.y * 128;
    const int n0 = blockIdx.x * 128;
    const int wm = (wid >> 1) * 64, wn = (wid & 1) * 64;
    const int fr = l & 15, fk = l >> 4;
    const int srow = l >> 3, slot = l & 7;

    f32x4 acc[4][4];
#pragma unroll
    for (int m = 0; m < 4; ++m)
#pragma unroll
        for (int n = 0; n < 4; ++n) acc[m][n] = (f32x4){0.f, 0.f, 0.f, 0.f};

    for (int kt = 0; kt < 8; ++kt) {
        const int k0 = kt * 64;
#pragma unroll
        for (int j = 0; j < 4; ++j) {
            const int r = wid * 32 + j * 8 + srow;
            const int cA = (slot ^ (r & 7)) * 8;       // pre-swizzled source
            const f16* gA = A + (size_t)(m0 + r) * 512 + k0 + cA;
            __builtin_amdgcn_global_load_lds(
                (const __attribute__((address_space(1))) unsigned int*)gA,
                (__attribute__((address_space(3))) unsigned int*)(As + wid * 2048 + j * 512),
                16, 0, 0);
            const f16* gB = Bt + (size_t)(n0 + r) * 512 + k0 + cA;
            __builtin_amdgcn_global_load_lds(
                (const __attribute__((address_space(1))) unsigned int*)gB,
                (__attribute__((address_space(3))) unsigned int*)(Bs + wid * 2048 + j * 512),
                16, 0, 0);
        }
        asm volatile("s_waitcnt vmcnt(0)" ::: "memory");
        __syncthreads();

        f16x8 af[4][2], bfr[4][2];
#pragma unroll
        for (int m = 0; m < 4; ++m) {
            const int row = wm + m * 16 + fr;
#pragma unroll
            for (int kk = 0; kk < 2; ++kk) {
                const int b = (kk * 64 + fk * 16) ^ ((row & 7) << 4);   // swz read
                af[m][kk] = *(const f16x8*)((const char*)As + row * 128 + b);
            }
        }
#pragma unroll
        for (int n = 0; n < 4; ++n) {
            const int row = wn + n * 16 + fr;
#pragma unroll
            for (int kk = 0; kk < 2; ++kk) {
                const int b = (kk * 64 + fk * 16) ^ ((row & 7) << 4);
                bfr[n][kk] = *(const f16x8*)((const char*)Bs + row * 128 + b);
            }
        }
#pragma unroll
        for (int kk = 0; kk < 2; ++kk)
#pragma unroll
            for (int m = 0; m < 4; ++m)
#pragma unroll
                for (int n = 0; n < 4; ++n)
                    acc[m][n] = __builtin_amdgcn_mfma_f32_16x16x32_f16(
                        af[m][kk], bfr[n][kk], acc[m][n], 0, 0, 0);
        __syncthreads();
    }

    // epilogue: C/D layout col = lane&15, row = (lane>>4)*4 + i  [m89]
    if (MODE == 0) {
#pragma unroll
        for (int nf = 0; nf < 4; ++nf) {
            const int ccol = n0 + wn + nf * 16 + fr;
            const int t = ccol >> 9;
            const int h = (ccol >> 6) & 7;
            const int d = ccol & 63;
            float* Cp = (t == 0) ? C0 : (t == 1) ? C1 : C2;
#pragma unroll
            for (int mf = 0; mf < 4; ++mf) {
#pragma unroll
                for (int i = 0; i < 4; ++i) {
                    const int grow = m0 + wm + mf * 16 + fk * 4 + i;
                    const int b_ = grow / NNODE;
                    const int nn = grow - b_ * NNODE;
                    Cp[((size_t)((b_ * NHEAD + h) * NNODE + nn)) * 64 + d] = acc[mf][nf][i];
                }
            }
        }
    } else {
#pragma unroll
        for (int nf = 0; nf < 4; ++nf) {
            const int ccol = n0 + wn + nf * 16 + fr;
#pragma unroll
            for (int mf = 0; mf < 4; ++mf) {
#pragma unroll
                for (int i = 0; i < 4; ++i) {
                    const int grow = m0 + wm + mf * 16 + fk * 4 + i;
                    C0[(size_t)grow * 512 + ccol] = acc[mf][nf][i];
                }
            }
        }
    }
}

// ---------------- attention v4 (unchanged structure) ----------------
// Block = 256 thr (4 waves), 4x8 query tile for one (b,h). One 37KB LDS
// buffer T time-shared: rotated-K (transposed [dpair][row], stride 145) for
// scores, then V for PV. RoPE by absolute position fused into staging.
__global__ __launch_bounds__(256, 4)
void attn4(const float* __restrict__ Qf, const float* __restrict__ Kf,
           const float* __restrict__ Vf, const float* __restrict__ freqs,
           f16* __restrict__ out2) {
    __shared__ float2 T[32 * TSTRIDE];

    const int tid = threadIdx.x;
    const int wid = tid >> 6, lane = tid & 63;
    const int qs = lane >> 3, wg = lane & 7;

    const int bid = blockIdx.x;
    const int t  = bid % 72, bh = bid / 72;
    const int tr = t % 12,   tc = t / 12;
    const int r0 = tr * 4,   c0 = tc * 8;
    const int h  = bh & 7,   b_ = bh >> 3;

    const int lr0 = max(0, r0 - 3), lr1 = min(HGRID - 1, r0 + 6);
    const int lc0 = max(0, c0 - 3), lc1 = min(WGRID - 1, c0 + 10);
    const int NR = lr1 - lr0 + 1, NC = lc1 - lc0 + 1;

    const float* Kb = Kf + (size_t)bh * NNODE * 64;
    const float* Vb = Vf + (size_t)bh * NNODE * 64;
    const float* fr_ = freqs + h * 64;
    const float* fc_ = freqs + h * 64 + 32;

    // ---- load + rotate Q row into registers (8 lanes share a row; L1 dedup)
    const int rq = r0 + wid, cq = c0 + qs;
    const int nq = rq * WGRID + cq;
    const float* qrow = Qf + (size_t)bh * NNODE * 64 + (size_t)nq * 64;
    float2 q2[32];
    {
        const float rfq = (float)rq, cfq = (float)cq;
#pragma unroll
        for (int j = 0; j < 16; ++j) {
            float4 v = *(const float4*)&qrow[j * 4];
            float th0 = rfq * fr_[2 * j]     + cfq * fc_[2 * j];
            float th1 = rfq * fr_[2 * j + 1] + cfq * fc_[2 * j + 1];
            float s0, c0v, s1, c1v;
            __sincosf(th0, &s0, &c0v);
            __sincosf(th1, &s1, &c1v);
            q2[2 * j]     = make_float2(v.x * c0v - v.y * s0, v.x * s0 + v.y * c0v);
            q2[2 * j + 1] = make_float2(v.z * c1v - v.w * s1, v.z * s1 + v.w * c1v);
        }
    }

    // ---- stage rotated K transposed: T[p*145 + row] ----
    const int cnt = NR * NC * 16;                    // one float4 (2 pairs) each
    for (int i = tid; i < cnt; i += 256) {
        const int row = i >> 4, p2 = i & 15;
        const int glr = row / NC, glc = row - glr * NC;
        const int rn = lr0 + glr, cn = lc0 + glc;
        const int n = rn * WGRID + cn;
        float4 v = *(const float4*)&Kb[(size_t)n * 64 + p2 * 4];
        const float rf = (float)rn, cf = (float)cn;
        const int p0 = 2 * p2;
        float th0 = rf * fr_[p0]     + cf * fc_[p0];
        float th1 = rf * fr_[p0 + 1] + cf * fc_[p0 + 1];
        float s0, c0v, s1, c1v;
        __sincosf(th0, &s0, &c0v);
        __sincosf(th1, &s1, &c1v);
        T[p0 * TSTRIDE + row]       = make_float2(v.x * c0v - v.y * s0, v.x * s0 + v.y * c0v);
        T[(p0 + 1) * TSTRIDE + row] = make_float2(v.z * c1v - v.w * s1, v.z * s1 + v.w * c1v);
    }
    __syncthreads();

    // ---- score phase: lane (qs,wg) -> neighbors w = wg + 8k ----
    float sc[7], es[7];
    float mx = -1e30f;
#pragma unroll
    for (int k = 0; k < 7; ++k) {
        const int w = wg + 8 * k;
        sc[k] = -1e30f;
        if (w < WSZ) {
            const int dr = w / 7 - RAD, dc = w % 7 - RAD;
            const int nr = rq + dr, nc = cq + dc;
            const bool valid = ((unsigned)nr < (unsigned)HGRID) &&
                               ((unsigned)nc < (unsigned)WGRID);
            const int nrl = min(max(nr, lr0), lr1) - lr0;
            const int ncl = min(max(nc, lc0), lc1) - lc0;
            const int row = nrl * NC + ncl;
            float s = 0.0f;
#pragma unroll
            for (int j = 0; j < 32; ++j) {
                float2 k2 = T[j * TSTRIDE + row];
                s = fmaf(q2[j].x, k2.x, s);
                s = fmaf(q2[j].y, k2.y, s);
            }
            sc[k] = valid ? s * SCALE : -1e9f;
            mx = fmaxf(mx, sc[k]);
        }
    }
#pragma unroll
    for (int o = 1; o < 8; o <<= 1) mx = fmaxf(mx, __shfl_xor(mx, o));
    float sum = 0.0f;
#pragma unroll
    for (int k = 0; k < 7; ++k) {
        const int w = wg + 8 * k;
        es[k] = 0.0f;
        if (w < WSZ) { es[k] = __expf(sc[k] - mx); sum += es[k]; }
    }
#pragma unroll
    for (int o = 1; o < 8; o <<= 1) sum += __shfl_xor(sum, o);
    const float inv = 1.0f / sum;
    float esn[7];
#pragma unroll
    for (int k = 0; k < 7; ++k) esn[k] = es[k] * inv;

    __syncthreads();   // all waves done reading K

    // ---- stage V (no rotation), same transposed layout ----
    for (int i = tid; i < cnt; i += 256) {
        const int row = i >> 4, p2 = i & 15;
        const int glr = row / NC, glc = row - glr * NC;
        const int n = (lr0 + glr) * WGRID + (lc0 + glc);
        float4 v = *(const float4*)&Vb[(size_t)n * 64 + p2 * 4];
        T[(2 * p2) * TSTRIDE + row]     = make_float2(v.x, v.y);
        T[(2 * p2 + 1) * TSTRIDE + row] = make_float2(v.z, v.w);
    }
    __syncthreads();

    // ---- PV phase: lane (qs,dg) accumulates 8 dims for q=(rq, c0+qs) ----
    const int dg = wg;
    float2 acc[4] = {{0, 0}, {0, 0}, {0, 0}, {0, 0}};
#pragma unroll
    for (int w = 0; w < WSZ; ++w) {
        const int dr = w / 7 - RAD, dc = w % 7 - RAD;
        const int nr = rq + dr, nc = cq + dc;
        const int nrl = min(max(nr, lr0), lr1) - lr0;
        const int ncl = min(max(nc, lc0), lc1) - lc0;
        const int row = nrl * NC + ncl;
        const float pw = __shfl(esn[w >> 3], (lane & 0x38) | (w & 7));
#pragma unroll
        for (int j = 0; j < 4; ++j) {
            float2 v2 = T[(dg * 4 + j) * TSTRIDE + row];
            acc[j].x = fmaf(pw, v2.x, acc[j].x);
            acc[j].y = fmaf(pw, v2.y, acc[j].y);
        }
    }

    // ---- write fp16 row for the W_O GEMM ----
    f16 o[8] = {(f16)acc[0].x, (f16)acc[0].y, (f16)acc[1].x, (f16)acc[1].y,
                (f16)acc[2].x, (f16)acc[2].y, (f16)acc[3].x, (f16)acc[3].y};
    const size_t rowb = (size_t)(b_ * NNODE + nq) * 512 + h * 64 + dg * 8;
    *(f16x8*)&out2[rowb] = *(f16x8*)o;
}

extern "C" void kernel_launch(void* const* d_in, const int* in_sizes, int n_in,
                              void* d_out, int out_size, void* d_ws, size_t ws_size,
                              hipStream_t stream) {
    const float* x     = (const float*)d_in[0];
    const float* WQ    = (const float*)d_in[2];
    const float* WK    = (const float*)d_in[3];
    const float* WV    = (const float*)d_in[4];
    const float* WO    = (const float*)d_in[5];
    const float* freqs = (const float*)d_in[7];

    float* Qf   = (float*)d_ws;
    float* Kf   = Qf + TEN;
    float* Vf   = Kf + TEN;
    f16*   x2   = (f16*)(Vf + TEN);                 // MROWS x 512
    f16*   Wall = x2 + (size_t)MROWS * 512;         // 2048 x 512 (QKV^T | WO^T)
    f16*   Wo2  = Wall + (size_t)1536 * 512;

    conv_x<<<(MROWS * 64 + 255) / 256, 256, 0, stream>>>(x, x2);
    conv_w<<<(2048 * 64 + 255) / 256, 256, 0, stream>>>(WQ, WK, WV, WO, Wall);

    dim3 gqkv(12, 36);   // 1536/128 x 4608/128
    mgemm<0><<<gqkv, 256, 0, stream>>>(x2, Wall, Qf, Kf, Vf);

    attn4<<<16 * 72, 256, 0, stream>>>(Qf, Kf, Vf, freqs, x2);

    dim3 go(4, 36);      // 512/128 x 4608/128
    mgemm<1><<<go, 256, 0, stream>>>(x2, Wo2, (float*)d_out, nullptr, nullptr);
}

// Round 7
// 64.822 us; speedup vs baseline: 5.9400x; 1.2418x over previous
//
#include <hip/hip_runtime.h>
#include <math.h>

// RelativePositionAttention on MI355X (gfx950)
//
// Algebraic simplifications (verified rounds 1-6, absmax <= 7.8e-3):
//  - U_ortho @ U_ortho^T == I -> skip QR projection entirely.
//  - RoPE factorizes: rotate Q,K by ABSOLUTE position (score invariant);
//    attention becomes plain masked sliding-window attention.
//  - GEMMs single-pass fp16 MFMA (K=512), fp32 accumulate.
//
// Round 7: RoPE fused into mgemm<0> epilogue (shfl_xor(1) partner + sincos on
// the GEMM's idle VALU); Q/K/V stored fp16 (halves attn fetch + LDS bytes);
// attn5 uses fp16 LDS (18KB -> 5 blocks/CU) and v_dot2_f32_f16 scores;
// conv_x/conv_w merged into one kernel.

#define BB 2
#define HGRID 48
#define WGRID 48
#define NNODE (HGRID*WGRID)   // 2304
#define RAD 3
#define WSZ 49
#define DMODEL 512
#define NHEAD 8
#define SCALE 0.125f
#define MROWS (BB*NNODE)      // 4608
#define TPAD 141              // half2 units; rows<=140

typedef _Float16 f16;
typedef __attribute__((ext_vector_type(8))) _Float16 f16x8;
typedef __attribute__((ext_vector_type(2))) _Float16 h2;
typedef __attribute__((ext_vector_type(4))) float f32x4;

typedef union { f16x8 v8; h2 h[4]; } pack8;

#if __has_builtin(__builtin_amdgcn_fdot2)
__device__ __forceinline__ float fdot2(h2 a, h2 b, float c) {
    return __builtin_amdgcn_fdot2(a, b, c, false);
}
#else
__device__ __forceinline__ float fdot2(h2 a, h2 b, float c) {
    return fmaf((float)a.x, (float)b.x, fmaf((float)a.y, (float)b.y, c));
}
#endif

// ------- one-shot conversion: x -> fp16 row-major, weights -> fp16 B^T ------
// id < MROWS*64: x rows. Else: np in [0,2048) = [WQ|WK|WV|WO] columns.
__global__ void convert_all(const float* __restrict__ x,
                            const float* __restrict__ WQ, const float* __restrict__ WK,
                            const float* __restrict__ WV, const float* __restrict__ WO,
                            f16* __restrict__ x2, f16* __restrict__ Wall) {
    int id = blockIdx.x * 256 + threadIdx.x;         // (MROWS+2048)*64
    if (id < MROWS * 64) {
        int r = id >> 6, c8 = (id & 63) << 3;
        float4 a = *(const float4*)&x[(size_t)r * 512 + c8];
        float4 b = *(const float4*)&x[(size_t)r * 512 + c8 + 4];
        f16 o[8] = {(f16)a.x, (f16)a.y, (f16)a.z, (f16)a.w,
                    (f16)b.x, (f16)b.y, (f16)b.z, (f16)b.w};
        *(f16x8*)&x2[(size_t)r * 512 + c8] = *(f16x8*)o;
        return;
    }
    id -= MROWS * 64;
    if (id >= 2048 * 64) return;
    int np = id >> 6;
    int kb = (id & 63) << 3;
    const float* S;
    int n;
    if (np < 1536) { int t = np >> 9; n = np & 511; S = (t == 0) ? WQ : (t == 1) ? WK : WV; }
    else           { n = np - 1536;  S = WO; }
    f16 o[8];
#pragma unroll
    for (int i = 0; i < 8; ++i) o[i] = (f16)S[(size_t)(kb + i) * 512 + n];
    *(f16x8*)&Wall[(size_t)np * 512 + kb] = *(f16x8*)o;
}

// ---------------- fp16 MFMA GEMM: 128x128 tile, BK=64, K=512, 4 waves ------
// MODE 0: NB=1536; epilogue rotates Q,K by absolute-position RoPE and writes
//         fp16 into Qh/Kh/Vh laid out (bh, n, d). MODE 1: NB=512, fp32 C.
template<int MODE>
__global__ __launch_bounds__(256)
void mgemm(const f16* __restrict__ A, const f16* __restrict__ Bt,
           f16* __restrict__ Qh, f16* __restrict__ Kh, f16* __restrict__ Vh,
           float* __restrict__ Cf, const float* __restrict__ freqs) {
    __shared__ f16 As[128 * 64];
    __shared__ f16 Bs[128 * 64];

    const int tid = threadIdx.x;
    const int l = tid & 63, wid = tid >> 6;
    const int m0 = blockIdx.y * 128;
    const int n0 = blockIdx.x * 128;
    const int wm = (wid >> 1) * 64, wn = (wid & 1) * 64;
    const int fr = l & 15, fk = l >> 4;
    const int srow = l >> 3, slot = l & 7;

    f32x4 acc[4][4];
#pragma unroll
    for (int m = 0; m < 4; ++m)
#pragma unroll
        for (int n = 0; n < 4; ++n) acc[m][n] = (f32x4){0.f, 0.f, 0.f, 0.f};

    for (int kt = 0; kt < 8; ++kt) {
        const int k0 = kt * 64;
#pragma unroll
        for (int j = 0; j < 4; ++j) {
            const int r = wid * 32 + j * 8 + srow;
            const int cA = (slot ^ (r & 7)) * 8;       // pre-swizzled source
            const f16* gA = A + (size_t)(m0 + r) * 512 + k0 + cA;
            __builtin_amdgcn_global_load_lds(
                (const __attribute__((address_space(1))) unsigned int*)gA,
                (__attribute__((address_space(3))) unsigned int*)(As + wid * 2048 + j * 512),
                16, 0, 0);
            const f16* gB = Bt + (size_t)(n0 + r) * 512 + k0 + cA;
            __builtin_amdgcn_global_load_lds(
                (const __attribute__((address_space(1))) unsigned int*)gB,
                (__attribute__((address_space(3))) unsigned int*)(Bs + wid * 2048 + j * 512),
                16, 0, 0);
        }
        asm volatile("s_waitcnt vmcnt(0)" ::: "memory");
        __syncthreads();

        f16x8 af[4][2], bfr[4][2];
#pragma unroll
        for (int m = 0; m < 4; ++m) {
            const int row = wm + m * 16 + fr;
#pragma unroll
            for (int kk = 0; kk < 2; ++kk) {
                const int b = (kk * 64 + fk * 16) ^ ((row & 7) << 4);   // swz read
                af[m][kk] = *(const f16x8*)((const char*)As + row * 128 + b);
            }
        }
#pragma unroll
        for (int n = 0; n < 4; ++n) {
            const int row = wn + n * 16 + fr;
#pragma unroll
            for (int kk = 0; kk < 2; ++kk) {
                const int b = (kk * 64 + fk * 16) ^ ((row & 7) << 4);
                bfr[n][kk] = *(const f16x8*)((const char*)Bs + row * 128 + b);
            }
        }
#pragma unroll
        for (int kk = 0; kk < 2; ++kk)
#pragma unroll
            for (int m = 0; m < 4; ++m)
#pragma unroll
                for (int n = 0; n < 4; ++n)
                    acc[m][n] = __builtin_amdgcn_mfma_f32_16x16x32_f16(
                        af[m][kk], bfr[n][kk], acc[m][n], 0, 0, 0);
        __syncthreads();
    }

    // epilogue: C/D layout col = lane&15, row = (lane>>4)*4 + i  [m89]
    if (MODE == 0) {
#pragma unroll
        for (int nf = 0; nf < 4; ++nf) {
            const int ccol = n0 + wn + nf * 16 + fr;
            const int t = ccol >> 9;              // uniform per block
            const int h = (ccol >> 6) & 7;
            const int d = ccol & 63;
            const int p = d >> 1;
            f16* Cp = (t == 0) ? Qh : (t == 1) ? Kh : Vh;
            const float fR = freqs[h * 64 + p];
            const float fC = freqs[h * 64 + 32 + p];
            const float sgn = (d & 1) ? 1.0f : -1.0f;
#pragma unroll
            for (int mf = 0; mf < 4; ++mf) {
#pragma unroll
                for (int i = 0; i < 4; ++i) {
                    const int grow = m0 + wm + mf * 16 + fk * 4 + i;
                    const int b_ = grow >= NNODE;
                    const int nn = grow - b_ * NNODE;
                    float val = acc[mf][nf][i];
                    float part = __shfl_xor(val, 1);     // pair partner (d^1)
                    float outv = val;
                    if (t < 2) {
                        float th = (float)(nn / WGRID) * fR + (float)(nn % WGRID) * fC;
                        float sn, cs;
                        __sincosf(th, &sn, &cs);
                        outv = fmaf(sgn * part, sn, val * cs);
                    }
                    Cp[((size_t)((b_ * NHEAD + h) * NNODE + nn)) * 64 + d] = (f16)outv;
                }
            }
        }
    } else {
#pragma unroll
        for (int nf = 0; nf < 4; ++nf) {
            const int ccol = n0 + wn + nf * 16 + fr;
#pragma unroll
            for (int mf = 0; mf < 4; ++mf) {
#pragma unroll
                for (int i = 0; i < 4; ++i) {
                    const int grow = m0 + wm + mf * 16 + fk * 4 + i;
                    Cf[(size_t)grow * 512 + ccol] = acc[mf][nf][i];
                }
            }
        }
    }
}

// ---------------- attention v5: fp16 LDS, fdot2 scores ----------------
// Block = 256 thr (4 waves), 4x8 query tile for one (b,h). One 18KB LDS
// buffer T (half2, transposed [dpair][row], stride 141) time-shared K -> V.
// Q/K/V already RoPE-rotated fp16. 5 blocks/CU.
__global__ __launch_bounds__(256, 5)
void attn5(const f16* __restrict__ Qh, const f16* __restrict__ Kh,
           const f16* __restrict__ Vh, f16* __restrict__ out2) {
    __shared__ h2 T[32 * TPAD];

    const int tid = threadIdx.x;
    const int wid = tid >> 6, lane = tid & 63;
    const int qs = lane >> 3, wg = lane & 7;

    const int bid = blockIdx.x;
    const int t  = bid % 72, bh = bid / 72;
    const int tr = t % 12,   tc = t / 12;
    const int r0 = tr * 4,   c0 = tc * 8;
    const int h  = bh & 7,   b_ = bh >> 3;

    const int lr0 = max(0, r0 - 3), lr1 = min(HGRID - 1, r0 + 6);
    const int lc0 = max(0, c0 - 3), lc1 = min(WGRID - 1, c0 + 10);
    const int NR = lr1 - lr0 + 1, NC = lc1 - lc0 + 1;

    const f16* Kb = Kh + (size_t)bh * NNODE * 64;
    const f16* Vb = Vh + (size_t)bh * NNODE * 64;

    // ---- Q row into registers as half2 pairs (pure reinterpret) ----
    const int rq = r0 + wid, cq = c0 + qs;
    const int nq = rq * WGRID + cq;
    const f16* qrow = Qh + ((size_t)bh * NNODE + nq) * 64;
    h2 q2[32];
#pragma unroll
    for (int j8 = 0; j8 < 8; ++j8) {
        pack8 v;
        v.v8 = *(const f16x8*)&qrow[j8 * 8];
#pragma unroll
        for (int k = 0; k < 4; ++k) q2[j8 * 4 + k] = v.h[k];
    }

    // ---- stage K (pure copy, transposed half2) ----
    const int cnt = NR * NC * 8;
    for (int i = tid; i < cnt; i += 256) {
        const int row = i >> 3, p4 = i & 7;
        const int glr = row / NC, glc = row - glr * NC;
        const int n = (lr0 + glr) * WGRID + (lc0 + glc);
        pack8 v;
        v.v8 = *(const f16x8*)&Kb[(size_t)n * 64 + p4 * 8];
#pragma unroll
        for (int j = 0; j < 4; ++j) T[(p4 * 4 + j) * TPAD + row] = v.h[j];
    }
    __syncthreads();

    // ---- score phase: lane (qs,wg) -> neighbors w = wg + 8k ----
    float sc[7], es[7];
    float mx = -1e30f;
#pragma unroll
    for (int k = 0; k < 7; ++k) {
        const int w = wg + 8 * k;
        sc[k] = -1e30f;
        if (w < WSZ) {
            const int dr = w / 7 - RAD, dc = w % 7 - RAD;
            const int nr = rq + dr, nc = cq + dc;
            const bool valid = ((unsigned)nr < (unsigned)HGRID) &&
                               ((unsigned)nc < (unsigned)WGRID);
            const int nrl = min(max(nr, lr0), lr1) - lr0;
            const int ncl = min(max(nc, lc0), lc1) - lc0;
            const int row = nrl * NC + ncl;
            float s = 0.0f;
#pragma unroll
            for (int j = 0; j < 32; ++j) s = fdot2(q2[j], T[j * TPAD + row], s);
            sc[k] = valid ? s * SCALE : -1e9f;
            mx = fmaxf(mx, sc[k]);
        }
    }
#pragma unroll
    for (int o = 1; o < 8; o <<= 1) mx = fmaxf(mx, __shfl_xor(mx, o));
    float sum = 0.0f;
#pragma unroll
    for (int k = 0; k < 7; ++k) {
        const int w = wg + 8 * k;
        es[k] = 0.0f;
        if (w < WSZ) { es[k] = __expf(sc[k] - mx); sum += es[k]; }
    }
#pragma unroll
    for (int o = 1; o < 8; o <<= 1) sum += __shfl_xor(sum, o);
    const float inv = 1.0f / sum;
    float esn[7];
#pragma unroll
    for (int k = 0; k < 7; ++k) esn[k] = es[k] * inv;

    __syncthreads();   // all waves done reading K

    // ---- stage V, same layout ----
    for (int i = tid; i < cnt; i += 256) {
        const int row = i >> 3, p4 = i & 7;
        const int glr = row / NC, glc = row - glr * NC;
        const int n = (lr0 + glr) * WGRID + (lc0 + glc);
        pack8 v;
        v.v8 = *(const f16x8*)&Vb[(size_t)n * 64 + p4 * 8];
#pragma unroll
        for (int j = 0; j < 4; ++j) T[(p4 * 4 + j) * TPAD + row] = v.h[j];
    }
    __syncthreads();

    // ---- PV phase: lane (qs,dg) accumulates 8 dims ----
    const int dg = wg;
    float2 acc[4] = {{0, 0}, {0, 0}, {0, 0}, {0, 0}};
#pragma unroll
    for (int w = 0; w < WSZ; ++w) {
        const int dr = w / 7 - RAD, dc = w % 7 - RAD;
        const int nr = rq + dr, nc = cq + dc;
        const int nrl = min(max(nr, lr0), lr1) - lr0;
        const int ncl = min(max(nc, lc0), lc1) - lc0;
        const int row = nrl * NC + ncl;
        const float pw = __shfl(esn[w >> 3], (lane & 0x38) | (w & 7));
#pragma unroll
        for (int j = 0; j < 4; ++j) {
            h2 v2 = T[(dg * 4 + j) * TPAD + row];
            acc[j].x = fmaf(pw, (float)v2.x, acc[j].x);
            acc[j].y = fmaf(pw, (float)v2.y, acc[j].y);
        }
    }

    // ---- write fp16 row for the W_O GEMM ----
    f16 o[8] = {(f16)acc[0].x, (f16)acc[0].y, (f16)acc[1].x, (f16)acc[1].y,
                (f16)acc[2].x, (f16)acc[2].y, (f16)acc[3].x, (f16)acc[3].y};
    const size_t rowb = (size_t)(b_ * NNODE + nq) * 512 + h * 64 + dg * 8;
    *(f16x8*)&out2[rowb] = *(f16x8*)o;
}

extern "C" void kernel_launch(void* const* d_in, const int* in_sizes, int n_in,
                              void* d_out, int out_size, void* d_ws, size_t ws_size,
                              hipStream_t stream) {
    const float* x     = (const float*)d_in[0];
    const float* WQ    = (const float*)d_in[2];
    const float* WK    = (const float*)d_in[3];
    const float* WV    = (const float*)d_in[4];
    const float* WO    = (const float*)d_in[5];
    const float* freqs = (const float*)d_in[7];

    const size_t HN = (size_t)16 * NNODE * 64;      // per Q/K/V fp16 tensor
    f16* Qh   = (f16*)d_ws;
    f16* Kh   = Qh + HN;
    f16* Vh   = Kh + HN;
    f16* x2   = Vh + HN;                            // MROWS x 512
    f16* Wall = x2 + (size_t)MROWS * 512;           // 2048 x 512
    f16* Wo2  = Wall + (size_t)1536 * 512;

    convert_all<<<((MROWS + 2048) * 64 + 255) / 256, 256, 0, stream>>>(
        x, WQ, WK, WV, WO, x2, Wall);

    dim3 gqkv(12, 36);   // 1536/128 x 4608/128
    mgemm<0><<<gqkv, 256, 0, stream>>>(x2, Wall, Qh, Kh, Vh, nullptr, freqs);

    attn5<<<16 * 72, 256, 0, stream>>>(Qh, Kh, Vh, x2);

    dim3 go(4, 36);      // 512/128 x 4608/128
    mgemm<1><<<go, 256, 0, stream>>>(x2, Wo2, nullptr, nullptr, nullptr,
                                     (float*)d_out, freqs);
}